// Round 6
// baseline (3289.461 us; speedup 1.0000x reference)
//
#include <hip/hip_runtime.h>
#include <hip/hip_bf16.h>
#include <stdint.h>

// ---------------------------------------------------------------------------
#define LSEQ 768
#define DM   256
#define NH   8
#define DK   32
#define DFF  1024
#define NLAYER 8
#define NDD  1535
// ---------------------------------------------------------------------------

typedef __attribute__((ext_vector_type(8))) short  bf16x8;
typedef __attribute__((ext_vector_type(4))) float  f32x4;

__device__ __forceinline__ unsigned short f2bf(float f) {
  unsigned u = __float_as_uint(f);
  u += 0x7fffu + ((u >> 16) & 1u);       // RNE
  return (unsigned short)(u >> 16);
}
__device__ __forceinline__ unsigned pk2(float a, float b) {
  __hip_bfloat162 h = __float22bfloat162_rn(make_float2(a, b));
  union { __hip_bfloat162 h; unsigned u; } c; c.h = h;
  return c.u;
}

// Agent-scope (L3-coherent) 8B ops — ONLY for tensors crossing XCDs within a
// dispatch. These bypass L2 entirely (each access = L3 round trip), so keep
// their volume minimal (round-5 lesson: 107 MB/layer of these = 305 us).
__device__ __forceinline__ float2 ld2(const float* p) {
  union { unsigned long long u; float2 f; } c;
  c.u = __hip_atomic_load((unsigned long long*)(uintptr_t)p,
                          __ATOMIC_RELAXED, __HIP_MEMORY_SCOPE_AGENT);
  return c.f;
}
__device__ __forceinline__ void st2(float* p, float2 f) {
  union { float2 f; unsigned long long u; } c; c.f = f;
  __hip_atomic_store((unsigned long long*)p, c.u,
                     __ATOMIC_RELAXED, __HIP_MEMORY_SCOPE_AGENT);
}
__device__ __forceinline__ float4 ld4a(const float* p) {
  float2 a = ld2(p), b = ld2(p + 2);
  return make_float4(a.x, a.y, b.x, b.y);
}
__device__ __forceinline__ void st4a(float* p, float4 v) {
  st2(p, make_float2(v.x, v.y));
  st2(p + 2, make_float2(v.z, v.w));
}

// Flag protocol (validated rounds 4-5): producer stores drained by
// __syncthreads' vmcnt(0), then one-lane agent atomic inc; consumer spins.
__device__ __forceinline__ void sigc(unsigned* c) {
  __syncthreads();
  if (threadIdx.x == 0)
    __hip_atomic_fetch_add(c, 1u, __ATOMIC_RELAXED, __HIP_MEMORY_SCOPE_AGENT);
}
__device__ __forceinline__ void waitc(unsigned* c, unsigned tgt) {
  if (threadIdx.x == 0) {
    while (__hip_atomic_load(c, __ATOMIC_RELAXED, __HIP_MEMORY_SCOPE_AGENT) < tgt)
      __builtin_amdgcn_s_sleep(1);
  }
  __syncthreads();
}

__device__ __forceinline__ int bucket_of(int dd) {
  int rel = dd - 767;
  int ret = rel < 0 ? 32 : 0;
  int arp = rel < 0 ? -rel : rel;
  if (arp < 16) return ret + arp;
  const float lr = 2.772588722239781f;   // float(np.log(16))
  float val = logf((float)arp * 0.0625f) / lr * 16.0f;
  int vi = 16 + (int)val;
  return ret + (vi < 31 ? vi : 31);
}

// ---------------------------------------------------------------------------
// WIDE GEMM tile: 64 rows x 256 cols, K streamed in 32-chunks. A read ONCE
// per tile (the expensive sc1 path); B (weights) staged LDS<-L2 per chunk.
// LDS carve from smc: As[32][68] @0 (8704), Bs[32][260] @8704 (33280),
// stat @41984 (512), red @42496 (2048) -> 44544.
template <int LN, int GELU, int RES, int ATOMIC, int ACOH, int CCOH>
__device__ void gemm_wide(const float* A, int lda,
                          const float* B, int ldb,
                          const float* bias, float* C, int ldc,
                          const float* res,
                          const float* lns, const float* lnb,
                          int K, int m0, int n0, char* smc) {
  float* As = (float*)smc;                    // [32][68]
  float* Bs = (float*)(smc + 8704);           // [32][260]
  float (*stat)[2] = (float (*)[2])(smc + 41984);
  float (*red)[8]  = (float (*)[8])(smc + 42496);

  int t = threadIdx.x;
  int arow = t >> 2, akq = (t & 3) * 8;
  const float* Ar = A + (size_t)(m0 + arow) * lda;

  float mean = 0.f, rstd = 0.f;
  if (LN) {
    int lq = t & 3;
    float s = 0.f, s2 = 0.f;
    const float* p = Ar + lq * 64;
    #pragma unroll
    for (int c = 0; c < 64; c += 4) {
      float4 v = ACOH ? ld4a(p + c) : *(const float4*)(p + c);
      s  += v.x + v.y + v.z + v.w;
      s2 += v.x * v.x + v.y * v.y + v.z * v.z + v.w * v.w;
    }
    red[arow][lq] = s; red[arow][lq + 4] = s2;
    __syncthreads();
    if (lq == 0) {
      float sm = red[arow][0] + red[arow][1] + red[arow][2] + red[arow][3];
      float sq = red[arow][4] + red[arow][5] + red[arow][6] + red[arow][7];
      float m = sm * (1.f / 256.f);
      float v = sq * (1.f / 256.f) - m * m;
      stat[arow][0] = m;
      stat[arow][1] = rsqrtf(v + 1e-5f);
    }
    __syncthreads();
    mean = stat[arow][0]; rstd = stat[arow][1];
  }

  int ty = t >> 4, tx = t & 15;
  float acc[4][16] = {};
  int nk = K >> 5;

  for (int kt = 0; kt < nk; ++kt) {
    int k0 = kt << 5;
    // A chunk -> regs (sc1 if ACOH) -> As (transposed [k][row])
    float4 a0 = ACOH ? ld4a(Ar + k0 + akq)     : *(const float4*)(Ar + k0 + akq);
    float4 a1 = ACOH ? ld4a(Ar + k0 + akq + 4) : *(const float4*)(Ar + k0 + akq + 4);
    if (LN) {
      float4 ls0 = *(const float4*)(lns + k0 + akq), ls1 = *(const float4*)(lns + k0 + akq + 4);
      float4 lb0 = *(const float4*)(lnb + k0 + akq), lb1 = *(const float4*)(lnb + k0 + akq + 4);
      a0.x=(a0.x-mean)*rstd*ls0.x+lb0.x; a0.y=(a0.y-mean)*rstd*ls0.y+lb0.y;
      a0.z=(a0.z-mean)*rstd*ls0.z+lb0.z; a0.w=(a0.w-mean)*rstd*ls0.w+lb0.w;
      a1.x=(a1.x-mean)*rstd*ls1.x+lb1.x; a1.y=(a1.y-mean)*rstd*ls1.y+lb1.y;
      a1.z=(a1.z-mean)*rstd*ls1.z+lb1.z; a1.w=(a1.w-mean)*rstd*ls1.w+lb1.w;
    }
    As[(akq+0)*68+arow]=a0.x; As[(akq+1)*68+arow]=a0.y;
    As[(akq+2)*68+arow]=a0.z; As[(akq+3)*68+arow]=a0.w;
    As[(akq+4)*68+arow]=a1.x; As[(akq+5)*68+arow]=a1.y;
    As[(akq+6)*68+arow]=a1.z; As[(akq+7)*68+arow]=a1.w;
    // B chunk 32x256 -> Bs (plain loads, L2-cached weights)
    #pragma unroll
    for (int i = 0; i < 8; ++i) {
      int f = t * 4 + i * 1024;
      int kkr = f >> 8, nc = f & 255;
      *(float4*)&Bs[kkr * 260 + nc] =
          *(const float4*)(B + (size_t)(k0 + kkr) * ldb + n0 + nc);
    }
    __syncthreads();
    #pragma unroll 8
    for (int kk = 0; kk < 32; ++kk) {
      float4 av = *(float4*)&As[kk * 68 + ty * 4];
      #pragma unroll
      for (int s = 0; s < 4; ++s) {
        float4 bv = *(float4*)&Bs[kk * 260 + s * 64 + tx * 4];
        acc[0][s*4+0]=fmaf(av.x,bv.x,acc[0][s*4+0]); acc[0][s*4+1]=fmaf(av.x,bv.y,acc[0][s*4+1]);
        acc[0][s*4+2]=fmaf(av.x,bv.z,acc[0][s*4+2]); acc[0][s*4+3]=fmaf(av.x,bv.w,acc[0][s*4+3]);
        acc[1][s*4+0]=fmaf(av.y,bv.x,acc[1][s*4+0]); acc[1][s*4+1]=fmaf(av.y,bv.y,acc[1][s*4+1]);
        acc[1][s*4+2]=fmaf(av.y,bv.z,acc[1][s*4+2]); acc[1][s*4+3]=fmaf(av.y,bv.w,acc[1][s*4+3]);
        acc[2][s*4+0]=fmaf(av.z,bv.x,acc[2][s*4+0]); acc[2][s*4+1]=fmaf(av.z,bv.y,acc[2][s*4+1]);
        acc[2][s*4+2]=fmaf(av.z,bv.z,acc[2][s*4+2]); acc[2][s*4+3]=fmaf(av.z,bv.w,acc[2][s*4+3]);
        acc[3][s*4+0]=fmaf(av.w,bv.x,acc[3][s*4+0]); acc[3][s*4+1]=fmaf(av.w,bv.y,acc[3][s*4+1]);
        acc[3][s*4+2]=fmaf(av.w,bv.z,acc[3][s*4+2]); acc[3][s*4+3]=fmaf(av.w,bv.w,acc[3][s*4+3]);
      }
    }
    __syncthreads();
  }

  #pragma unroll
  for (int u = 0; u < 4; ++u) {
    int m = m0 + ty * 4 + u;
    #pragma unroll
    for (int s = 0; s < 4; ++s) {
      int n = n0 + s * 64 + tx * 4;
      float4 val = make_float4(acc[u][s*4+0], acc[u][s*4+1], acc[u][s*4+2], acc[u][s*4+3]);
      if (bias) {
        float4 bv = *(const float4*)(bias + n);
        val.x += bv.x; val.y += bv.y; val.z += bv.z; val.w += bv.w;
      }
      if (GELU) {
        val.x = 0.5f * val.x * (1.f + erff(val.x * 0.70710678118654752f));
        val.y = 0.5f * val.y * (1.f + erff(val.y * 0.70710678118654752f));
        val.z = 0.5f * val.z * (1.f + erff(val.z * 0.70710678118654752f));
        val.w = 0.5f * val.w * (1.f + erff(val.w * 0.70710678118654752f));
      }
      if (RES) {
        float4 r = *(const float4*)(res + (size_t)m * ldc + n);
        val.x += r.x; val.y += r.y; val.z += r.z; val.w += r.w;
      }
      if (ATOMIC) {
        atomicAdd(&C[(size_t)m * ldc + n + 0], val.x);
        atomicAdd(&C[(size_t)m * ldc + n + 1], val.y);
        atomicAdd(&C[(size_t)m * ldc + n + 2], val.z);
        atomicAdd(&C[(size_t)m * ldc + n + 3], val.w);
      } else if (CCOH) {
        st4a(C + (size_t)m * ldc + n, val);
      } else {
        *(float4*)(C + (size_t)m * ldc + n) = val;
      }
    }
  }
}

// ---------------------------------------------------------------------------
// Legacy 64x64 GEMM tile (used by k_prep only; all plain caching).
// LDS from smc: As 2x32x68 @0, Bs @17408, stat @34816, red @35328 -> 37376.
template <int LN, int GR>
__device__ void gemm_tile(const float* gsrc, const int* seqIdx,
                          const float* B, const float* bias, float* C,
                          const float* lns, const float* lnb,
                          int M, int K, int N, int m0, int n0, char* smc) {
  float (*As)[32][68] = (float (*)[32][68])smc;
  float (*Bs)[32][68] = (float (*)[32][68])(smc + 17408);
  float (*stat)[2]    = (float (*)[2])(smc + 34816);
  float (*red)[8]     = (float (*)[8])(smc + 35328);

  int t = threadIdx.x;
  int arow = t >> 2, akq = (t & 3) * 8;
  int mg = m0 + arow;
  int mgc = mg < M ? mg : M - 1;
  const float* Ar = (GR == 1) ? (gsrc + (size_t)seqIdx[mgc] * K)
                              : (gsrc + (size_t)bucket_of(mgc) * K);
  float mean = 0.f, rstd = 0.f;
  if (LN) {
    int lq = t & 3;
    float s = 0.f, s2 = 0.f;
    const float* p = Ar + lq * 64;
    #pragma unroll
    for (int c = 0; c < 64; c += 4) {
      float4 v = *(const float4*)(p + c);
      s  += v.x + v.y + v.z + v.w;
      s2 += v.x * v.x + v.y * v.y + v.z * v.z + v.w * v.w;
    }
    red[arow][lq] = s; red[arow][lq + 4] = s2;
    __syncthreads();
    if (lq == 0) {
      float sm = red[arow][0] + red[arow][1] + red[arow][2] + red[arow][3];
      float sq = red[arow][4] + red[arow][5] + red[arow][6] + red[arow][7];
      float m = sm * (1.f / 256.f);
      float v = sq * (1.f / 256.f) - m * m;
      stat[arow][0] = m;
      stat[arow][1] = rsqrtf(v + 1e-5f);
    }
    __syncthreads();
    mean = stat[arow][0]; rstd = stat[arow][1];
  }

  int bkr = t >> 3, bn8 = (t & 7) * 8;
  int ty = t >> 4, tx = t & 15;
  float acc[4][4] = {};
  int nk = K >> 5;

  for (int kt = 0; kt < nk; ++kt) {
    int k0 = kt << 5;
    float4 a0 = *(const float4*)(Ar + k0 + akq);
    float4 a1 = *(const float4*)(Ar + k0 + akq + 4);
    if (LN) {
      float4 ls0 = *(const float4*)(lns + k0 + akq), ls1 = *(const float4*)(lns + k0 + akq + 4);
      float4 lb0 = *(const float4*)(lnb + k0 + akq), lb1 = *(const float4*)(lnb + k0 + akq + 4);
      a0.x=(a0.x-mean)*rstd*ls0.x+lb0.x; a0.y=(a0.y-mean)*rstd*ls0.y+lb0.y;
      a0.z=(a0.z-mean)*rstd*ls0.z+lb0.z; a0.w=(a0.w-mean)*rstd*ls0.w+lb0.w;
      a1.x=(a1.x-mean)*rstd*ls1.x+lb1.x; a1.y=(a1.y-mean)*rstd*ls1.y+lb1.y;
      a1.z=(a1.z-mean)*rstd*ls1.z+lb1.z; a1.w=(a1.w-mean)*rstd*ls1.w+lb1.w;
    }
    int cur = kt & 1;
    As[cur][akq+0][arow]=a0.x; As[cur][akq+1][arow]=a0.y; As[cur][akq+2][arow]=a0.z; As[cur][akq+3][arow]=a0.w;
    As[cur][akq+4][arow]=a1.x; As[cur][akq+5][arow]=a1.y; As[cur][akq+6][arow]=a1.z; As[cur][akq+7][arow]=a1.w;
    *(float4*)&Bs[cur][bkr][bn8] = *(const float4*)(B + (size_t)(k0 + bkr) * N + n0 + bn8);
    *(float4*)&Bs[cur][bkr][bn8+4] = *(const float4*)(B + (size_t)(k0 + bkr) * N + n0 + bn8 + 4);
    __syncthreads();
    #pragma unroll 8
    for (int kk = 0; kk < 32; ++kk) {
      float4 a = *(float4*)&As[cur][kk][ty * 4];
      float4 b = *(float4*)&Bs[cur][kk][tx * 4];
      acc[0][0]=fmaf(a.x,b.x,acc[0][0]); acc[0][1]=fmaf(a.x,b.y,acc[0][1]);
      acc[0][2]=fmaf(a.x,b.z,acc[0][2]); acc[0][3]=fmaf(a.x,b.w,acc[0][3]);
      acc[1][0]=fmaf(a.y,b.x,acc[1][0]); acc[1][1]=fmaf(a.y,b.y,acc[1][1]);
      acc[1][2]=fmaf(a.y,b.z,acc[1][2]); acc[1][3]=fmaf(a.y,b.w,acc[1][3]);
      acc[2][0]=fmaf(a.z,b.x,acc[2][0]); acc[2][1]=fmaf(a.z,b.y,acc[2][1]);
      acc[2][2]=fmaf(a.z,b.z,acc[2][2]); acc[2][3]=fmaf(a.z,b.w,acc[2][3]);
      acc[3][0]=fmaf(a.w,b.x,acc[3][0]); acc[3][1]=fmaf(a.w,b.y,acc[3][1]);
      acc[3][2]=fmaf(a.w,b.z,acc[3][2]); acc[3][3]=fmaf(a.w,b.w,acc[3][3]);
    }
    __syncthreads();
  }

  #pragma unroll
  for (int u = 0; u < 4; ++u) {
    int m = m0 + ty * 4 + u;
    if (m < M) {
      int n = n0 + tx * 4;
      float4 val = make_float4(acc[u][0], acc[u][1], acc[u][2], acc[u][3]);
      if (bias) {
        float4 bv = *(const float4*)(bias + n);
        val.x += bv.x; val.y += bv.y; val.z += bv.z; val.w += bv.w;
      }
      *(float4*)(C + (size_t)m * N + n) = val;
    }
  }
}

// ---------------------------------------------------------------------------
// Attention task: 16 q-rows x 1 head. Inputs plain (cross-dispatch, L2);
// only o store is agent-coherent. LDS: S[16][776] @0, red @49664,
// mrow @50688, linv @50752, pr @50816 (9216) -> 60032.
__device__ void attn_task(const float* q, const float* k, const float* v,
                          const float* abias, float* o, int i0, int h, char* smc) {
  float* S = (float*)smc;
  float (*red)[16] = (float (*)[16])(smc + 49664);
  float* mrow = (float*)(smc + 50688);
  float* linv = (float*)(smc + 50752);
  float* pr   = (float*)(smc + 50816);

  int hc = h * DK;
  int t = threadIdx.x;
  int ti = t >> 4, tj = t & 15;

  float qr[32];
  {
    const float* qp = q + (size_t)(i0 + ti) * DM + hc;
    const float inv = 0.17677669529663687f;   // 1/sqrt(32)
    #pragma unroll
    for (int c = 0; c < 32; c += 4) {
      float4 v4 = *(const float4*)(qp + c);
      qr[c+0] = v4.x * inv; qr[c+1] = v4.y * inv;
      qr[c+2] = v4.z * inv; qr[c+3] = v4.w * inv;
    }
  }

  float mx = -1e30f;
  for (int jc = 0; jc < 48; ++jc) {
    int j = jc * 16 + tj;
    const float* kr = k + (size_t)j * DM + hc;
    float acc = 0.f;
    #pragma unroll
    for (int c = 0; c < 32; c += 4) {
      float4 kv = *(const float4*)(kr + c);
      acc = fmaf(qr[c+0], kv.x, acc);
      acc = fmaf(qr[c+1], kv.y, acc);
      acc = fmaf(qr[c+2], kv.z, acc);
      acc = fmaf(qr[c+3], kv.w, acc);
    }
    acc += abias[(size_t)(i0 + ti - j + 767) * 8 + h];
    S[ti * 776 + j] = acc;
    mx = fmaxf(mx, acc);
  }
  red[ti][tj] = mx;
  __syncthreads();
  if (tj == 0) {
    float m2 = red[ti][0];
    #pragma unroll
    for (int u = 1; u < 16; ++u) m2 = fmaxf(m2, red[ti][u]);
    mrow[ti] = m2;
  }
  __syncthreads();
  float m2 = mrow[ti];
  float sum = 0.f;
  for (int jc = 0; jc < 48; ++jc) {
    int j = jc * 16 + tj;
    float e = __expf(S[ti * 776 + j] - m2);
    S[ti * 776 + j] = e;
    sum += e;
  }
  red[ti][tj] = sum;
  __syncthreads();
  if (tj == 0) {
    float s2 = 0.f;
    #pragma unroll
    for (int u = 0; u < 16; ++u) s2 += red[ti][u];
    linv[ti] = 1.f / s2;
  }
  __syncthreads();

  {
    int wv = t >> 6, l = t & 63;
    int c4 = (l & 7) * 4;
    int ib = l >> 3;
    float a00=0,a01=0,a02=0,a03=0, a10=0,a11=0,a12=0,a13=0;
    const float* vp = v + hc + c4;
    int jbeg = wv * 192;
    for (int j = jbeg; j < jbeg + 192; j += 4) {
      float4 s0 = *(float4*)&S[ib * 776 + j];
      float4 s1 = *(float4*)&S[(ib + 8) * 776 + j];
      const float* vj = vp + (size_t)j * DM;
      float4 v0 = *(const float4*)(vj);
      float4 v1 = *(const float4*)(vj + DM);
      float4 v2 = *(const float4*)(vj + 2 * DM);
      float4 v3 = *(const float4*)(vj + 3 * DM);
      a00=fmaf(s0.x,v0.x,a00); a01=fmaf(s0.x,v0.y,a01); a02=fmaf(s0.x,v0.z,a02); a03=fmaf(s0.x,v0.w,a03);
      a10=fmaf(s1.x,v0.x,a10); a11=fmaf(s1.x,v0.y,a11); a12=fmaf(s1.x,v0.z,a12); a13=fmaf(s1.x,v0.w,a13);
      a00=fmaf(s0.y,v1.x,a00); a01=fmaf(s0.y,v1.y,a01); a02=fmaf(s0.y,v1.z,a02); a03=fmaf(s0.y,v1.w,a03);
      a10=fmaf(s1.y,v1.x,a10); a11=fmaf(s1.y,v1.y,a11); a12=fmaf(s1.y,v1.z,a12); a13=fmaf(s1.y,v1.w,a13);
      a00=fmaf(s0.z,v2.x,a00); a01=fmaf(s0.z,v2.y,a01); a02=fmaf(s0.z,v2.z,a02); a03=fmaf(s0.z,v2.w,a03);
      a10=fmaf(s1.z,v2.x,a10); a11=fmaf(s1.z,v2.y,a11); a12=fmaf(s1.z,v2.z,a12); a13=fmaf(s1.z,v2.w,a13);
      a00=fmaf(s0.w,v3.x,a00); a01=fmaf(s0.w,v3.y,a01); a02=fmaf(s0.w,v3.z,a02); a03=fmaf(s0.w,v3.w,a03);
      a10=fmaf(s1.w,v3.x,a10); a11=fmaf(s1.w,v3.y,a11); a12=fmaf(s1.w,v3.z,a12); a13=fmaf(s1.w,v3.w,a13);
    }
    pr[(ib * 4 + wv) * 36 + c4 + 0] = a00;
    pr[(ib * 4 + wv) * 36 + c4 + 1] = a01;
    pr[(ib * 4 + wv) * 36 + c4 + 2] = a02;
    pr[(ib * 4 + wv) * 36 + c4 + 3] = a03;
    pr[((ib + 8) * 4 + wv) * 36 + c4 + 0] = a10;
    pr[((ib + 8) * 4 + wv) * 36 + c4 + 1] = a11;
    pr[((ib + 8) * 4 + wv) * 36 + c4 + 2] = a12;
    pr[((ib + 8) * 4 + wv) * 36 + c4 + 3] = a13;
  }
  __syncthreads();
  {
    int idx = t * 2;
    int i = idx >> 5, c = idx & 31;
    float s0 = pr[(i*4+0)*36 + c] + pr[(i*4+1)*36 + c]
             + pr[(i*4+2)*36 + c] + pr[(i*4+3)*36 + c];
    float s1 = pr[(i*4+0)*36 + c+1] + pr[(i*4+1)*36 + c+1]
             + pr[(i*4+2)*36 + c+1] + pr[(i*4+3)*36 + c+1];
    st2(o + (size_t)(i0 + i) * DM + hc + c,
        make_float2(s0 * linv[i], s1 * linv[i]));
  }
}

// ---------------------------------------------------------------------------
// One transformer layer, flag-pipelined. grid=396 (co-resident, 2/CU).
//  A attn (b 0..383): signal c_o[mg] (tgt 32, mg = 64-row group)
//  B wo   (b 384..395): wait c_o[m]=32; 64x256 + residual; signal c_x[m]
//  C ffn1 (b 0..47): wait c_x[m]=1; 64x256-chunk of f1; signal c_f[m] (tgt 4)
//  D ffn2 (b 48..95): wait c_f[m]=4 (all readers done); atomicAdd; sig c_x2[m]
//  E qkv/pair (b 96..131 / 96..119): wait c_x2[m]=4
struct LArgs {
  const float *qin, *kin, *vin, *xin, *abias;
  float *qout, *kout, *vout, *xout, *o, *f1;
  const float *wo, *ln2s, *ln2b, *fw1, *fb1, *fw2, *fb2;
  const float *wnq, *wnk, *wnv, *lnns, *lnnb, *nqb, *nkb;
  unsigned* cnt;
  int last;
};

__global__ __launch_bounds__(256, 2) void k_layer(LArgs a) {
  __shared__ __align__(16) char sm[60032];
  int b = blockIdx.x;
  unsigned* c_o  = a.cnt;
  unsigned* c_x  = a.cnt + 16;
  unsigned* c_f  = a.cnt + 32;
  unsigned* c_x2 = a.cnt + 48;

  if (b < 384) {
    attn_task(a.qin, a.kin, a.vin, a.abias, a.o, (b % 48) * 16, b / 48, sm);
    sigc(&c_o[(b % 48) >> 2]);
  }
  if (b >= 384) {          // B: xout = xin + o @ Wo  (12 blocks, full width)
    int m = b - 384;
    waitc(&c_o[m], 32);
    gemm_wide<0,0,1,0,1,1>(a.o, 256, a.wo, 256, nullptr, a.xout, 256,
                           a.xin, nullptr, nullptr, 256, m * 64, 0, sm);
    sigc(&c_x[m]);
  }
  if (b < 48) {            // C: f1 chunk = gelu(LN2(xout)@fw1+fb1)
    int m = b >> 2, nq = b & 3;
    waitc(&c_x[m], 1);
    gemm_wide<1,1,0,0,1,1>(a.xout, 256, a.fw1, 1024, a.fb1 + nq * 256,
                           a.f1, 1024, nullptr, a.ln2s, a.ln2b,
                           256, m * 64, nq * 256, sm);
    sigc(&c_f[m]);
  }
  if (b >= 48 && b < 96) { // D: xout += f1@fw2 (+fb2 on ks==0), split-K=4
    int td = b - 48, m = td >> 2, ks = td & 3;
    waitc(&c_f[m], 4);
    gemm_wide<0,0,0,1,1,0>(a.f1 + ks * 256, 1024,
                           a.fw2 + (size_t)(ks * 256) * 256, 256,
                           ks == 0 ? a.fb2 : nullptr, a.xout, 256,
                           nullptr, nullptr, nullptr, 256, m * 64, 0, sm);
    sigc(&c_x2[m]);
  }
  if (b >= 96 && b < 132) { // E: next qkv (36) or pair proj (24)
    if (!a.last) {
      int te = b - 96, m = te / 3, nc = te % 3;
      const float* B = nc == 0 ? a.wnq : (nc == 1 ? a.wnk : a.wnv);
      float* C = nc == 0 ? a.qout : (nc == 1 ? a.kout : a.vout);
      waitc(&c_x2[m], 4);
      gemm_wide<1,0,0,0,1,0>(a.xout, 256, B, 256, nullptr, C, 256,
                             nullptr, a.lnns, a.lnnb, 256, m * 64, 0, sm);
    } else if (b < 120) {
      int te = b - 96, m = te >> 1, pk_ = te & 1;
      waitc(&c_x2[m], 4);
      gemm_wide<1,0,0,0,1,0>(a.xout, 256, pk_ ? a.wnk : a.wnq, 256,
                             pk_ ? a.nkb : a.nqb, pk_ ? a.kout : a.qout, 256,
                             nullptr, a.lnns, a.lnnb, 256, m * 64, 0, sm);
    }
  }
}

// ---------------------------------------------------------------------------
// Prep: RB gemm + qkv layer0 + embed + abias + W1p pack. One dispatch.
__global__ __launch_bounds__(256, 2) void k_prep(
    const int* __restrict__ seq, const float* __restrict__ tok_emb,
    const float* __restrict__ rp_emb,
    const float* __restrict__ wq0, const float* __restrict__ wk0,
    const float* __restrict__ wv0,
    const float* __restrict__ ln1s0, const float* __restrict__ ln1b0,
    const float* __restrict__ pair_rp, const float* __restrict__ cls_w1,
    const float* __restrict__ cls_b1,
    float* x0, float* q0, float* k0, float* v0, float* RB,
    unsigned short* W1p, float* abias) {
  __shared__ __align__(16) char sm[37376];
  int b = blockIdx.x, t = threadIdx.x;
  if (b < 96) {
    int m0 = (b % 24) * 64, n0 = (b / 24) * 64;
    gemm_tile<0,2>(pair_rp, nullptr, cls_w1, cls_b1, RB,
                   nullptr, nullptr, NDD, 256, 256, m0, n0, sm);
  } else if (b < 240) {
    int u = b - 96;
    int n0g = (u % 12) * 64, m0 = (u / 12) * 64;
    int bi = n0g >> 8, n0 = n0g & 255;
    const float* B = bi == 0 ? wq0 : (bi == 1 ? wk0 : wv0);
    float* C = bi == 0 ? q0 : (bi == 1 ? k0 : v0);
    gemm_tile<1,1>(tok_emb, seq, B, nullptr, C,
                   ln1s0, ln1b0, LSEQ, 256, 256, m0, n0, sm);
  } else if (b < 432) {
    int row = (b - 240) * 4 + (t >> 6), c = (t & 63) * 4;
    *(float4*)(x0 + (size_t)row * DM + c) =
        *(const float4*)(tok_emb + (size_t)seq[row] * DM + c);
  } else if (b < 438) {
    int dd = (b - 432) * 256 + t;
    if (dd < NDD) {
      int bk = bucket_of(dd);
      #pragma unroll
      for (int h = 0; h < NH; ++h) abias[dd * 8 + h] = rp_emb[bk * 8 + h];
    }
  } else {
    int base = (b - 438) * 1024 + t * 4;
    #pragma unroll
    for (int uu = 0; uu < 4; ++uu) {
      int id = base + uu;
      int e = id & 7, lane = (id >> 3) & 63, g = (id >> 9) & 15, kc = id >> 13;
      int kg = kc * 32 + (lane >> 4) * 8 + e;
      int n  = g * 16 + (lane & 15);
      W1p[id] = f2bf(cls_w1[(size_t)kg * 256 + n]);
    }
  }
}

// ---------------------------------------------------------------------------
// Fused pair head (round-5 v3: LDS-staged q/k, W1p reg-prefetch, packed cvt).
#define PAIR_SMEM 74864

__global__ __launch_bounds__(256, 2) void k_pair(
    const float* __restrict__ pq, const float* __restrict__ pk,
    const unsigned short* __restrict__ W1p, const float* __restrict__ RB,
    const float* __restrict__ w2, const float* __restrict__ b2,
    float* __restrict__ out) {
  extern __shared__ char smem[];
  float* qs   = (float*)smem;
  float* ks   = (float*)(smem + 4160);
  float* RB_s = (float*)(smem + 37440);
  float* racc = (float*)(smem + 73840);

  int t = threadIdx.x;
  int j0 = blockIdx.x * 32;
  int i0 = blockIdx.y * 4;
  int w = t >> 6, l = t & 63;
  int q4 = l >> 4, l15 = l & 15;
  int mwv = w & 1, nwv = w >> 1;

  {
    int row = t >> 6, c4 = (t & 63) * 4;
    *(float4*)(qs + row * 260 + c4) = *(const float4*)(pq + (size_t)(i0 + row) * DM + c4);
    #pragma unroll
    for (int r8 = 0; r8 < 8; ++r8) {
      int idx = t + r8 * 256;
      int kr = idx >> 6, kc4 = (idx & 63) * 4;
      *(float4*)(ks + kr * 260 + kc4) = *(const float4*)(pk + (size_t)(j0 + kr) * DM + kc4);
    }
    int ddmin = i0 - j0 + 736;
    for (int idx = t; idx < 35 * 64; idx += 256) {
      int lc = idx >> 6, c4b = (idx & 63) * 4;
      *(float4*)(RB_s + lc * 260 + c4b) =
          *(const float4*)(RB + (size_t)(ddmin + lc) * 256 + c4b);
    }
    racc[t] = 0.f;
  }
  __syncthreads();

  const unsigned short* Bp = W1p + (size_t)(nwv * 8) * 512 + (size_t)l * 8;
  const float* q0p = qs + (mwv * 2) * 260;
  const float* q1p = qs + (mwv * 2 + 1) * 260;
  const float* k0p = ks + l15 * 260;
  const float* k1p = ks + (16 + l15) * 260;

  f32x4 acc[4][8];
  #pragma unroll
  for (int aa = 0; aa < 4; ++aa)
    #pragma unroll
    for (int bb = 0; bb < 8; ++bb) acc[aa][bb] = (f32x4){0.f, 0.f, 0.f, 0.f};

  bf16x8 bcur[8];
  #pragma unroll
  for (int nt = 0; nt < 8; ++nt) bcur[nt] = *(const bf16x8*)(Bp + nt * 512);

  for (int kc = 0; kc < 8; ++kc) {
    bf16x8 bnxt[8];
    if (kc < 7) {
      const unsigned short* bbn = Bp + (size_t)(kc + 1) * 8192;
      #pragma unroll
      for (int nt = 0; nt < 8; ++nt) bnxt[nt] = *(const bf16x8*)(bbn + nt * 512);
    }
    int c = kc * 32 + q4 * 8;
    float4 qa0 = *(const float4*)(q0p + c), qa1 = *(const float4*)(q0p + c + 4);
    float4 qb0 = *(const float4*)(q1p + c), qb1 = *(const float4*)(q1p + c + 4);
    float4 ka0 = *(const float4*)(k0p + c), ka1 = *(const float4*)(k0p + c + 4);
    float4 kb0 = *(const float4*)(k1p + c), kb1 = *(const float4*)(k1p + c + 4);

    union { bf16x8 v; unsigned u[4]; } af[4];
    af[0].u[0] = pk2(qa0.x*ka0.x, qa0.y*ka0.y); af[0].u[1] = pk2(qa0.z*ka0.z, qa0.w*ka0.w);
    af[0].u[2] = pk2(qa1.x*ka1.x, qa1.y*ka1.y); af[0].u[3] = pk2(qa1.z*ka1.z, qa1.w*ka1.w);
    af[1].u[0] = pk2(qa0.x*kb0.x, qa0.y*kb0.y); af[1].u[1] = pk2(qa0.z*kb0.z, qa0.w*kb0.w);
    af[1].u[2] = pk2(qa1.x*kb1.x, qa1.y*kb1.y); af[1].u[3] = pk2(qa1.z*kb1.z, qa1.w*kb1.w);
    af[2].u[0] = pk2(qb0.x*ka0.x, qb0.y*ka0.y); af[2].u[1] = pk2(qb0.z*ka0.z, qb0.w*ka0.w);
    af[2].u[2] = pk2(qb1.x*ka1.x, qb1.y*ka1.y); af[2].u[3] = pk2(qb1.z*ka1.z, qb1.w*ka1.w);
    af[3].u[0] = pk2(qb0.x*kb0.x, qb0.y*kb0.y); af[3].u[1] = pk2(qb0.z*kb0.z, qb0.w*kb0.w);
    af[3].u[2] = pk2(qb1.x*kb1.x, qb1.y*kb1.y); af[3].u[3] = pk2(qb1.z*kb1.z, qb1.w*kb1.w);

    #pragma unroll
    for (int mt = 0; mt < 4; ++mt)
      #pragma unroll
      for (int nt = 0; nt < 8; ++nt)
        acc[mt][nt] = __builtin_amdgcn_mfma_f32_16x16x32_bf16(af[mt].v, bcur[nt], acc[mt][nt], 0, 0, 0);
    if (kc < 7) {
      #pragma unroll
      for (int nt = 0; nt < 8; ++nt) bcur[nt] = bnxt[nt];
    }
  }

  float w20[8], w21[8];
  #pragma unroll
  for (int nt = 0; nt < 8; ++nt) {
    int n = nwv * 128 + nt * 16 + l15;
    w20[nt] = w2[n * 2];
    w21[nt] = w2[n * 2 + 1];
  }
  #pragma unroll
  for (int mt = 0; mt < 4; ++mt) {
    #pragma unroll
    for (int reg = 0; reg < 4; ++reg) {
      int r = mwv * 64 + mt * 16 + q4 * 4 + reg;
      int lc = (r >> 5) - (r & 31) + 31;
      float o0 = 0.f, o1 = 0.f;
      #pragma unroll
      for (int nt = 0; nt < 8; ++nt) {
        int n = nwv * 128 + nt * 16 + l15;
        float T = acc[mt][nt][reg] + RB_s[lc * 260 + n];
        T = fmaxf(T, 0.f);
        o0 = fmaf(T, w20[nt], o0);
        o1 = fmaf(T, w21[nt], o1);
      }
      #pragma unroll
      for (int s = 1; s < 16; s <<= 1) {
        o0 += __shfl_xor(o0, s);
        o1 += __shfl_xor(o1, s);
      }
      if (l15 == 0) {
        atomicAdd(&racc[r * 2 + 0], o0);
        atomicAdd(&racc[r * 2 + 1], o1);
      }
    }
  }
  __syncthreads();
  {
    int r = t >> 1, oo = t & 1;
    out[((size_t)(i0 + (r >> 5)) * LSEQ + (j0 + (r & 31))) * 2 + oo] = racc[t] + b2[oo];
  }
}

// ---------------------------------------------------------------------------
extern "C" void kernel_launch(void* const* d_in, const int* in_sizes, int n_in,
                              void* d_out, int out_size, void* d_ws, size_t ws_size,
                              hipStream_t stream) {
  const int*   seq      = (const int*)  d_in[0];
  const float* tok_emb  = (const float*)d_in[1];
  const float* rp_emb   = (const float*)d_in[2];
  const float* wq       = (const float*)d_in[3];
  const float* wk       = (const float*)d_in[4];
  const float* wv       = (const float*)d_in[5];
  const float* wo       = (const float*)d_in[6];
  const float* ln1_s    = (const float*)d_in[7];
  const float* ln1_b    = (const float*)d_in[8];
  const float* ln2_s    = (const float*)d_in[9];
  const float* ln2_b    = (const float*)d_in[10];
  const float* ffn_w1   = (const float*)d_in[11];
  const float* ffn_b1   = (const float*)d_in[12];
  const float* ffn_w2   = (const float*)d_in[13];
  const float* ffn_b2   = (const float*)d_in[14];
  const float* lnf_s    = (const float*)d_in[15];
  const float* lnf_b    = (const float*)d_in[16];
  const float* pair_q_w = (const float*)d_in[17];
  const float* pair_q_b = (const float*)d_in[18];
  const float* pair_k_w = (const float*)d_in[19];
  const float* pair_k_b = (const float*)d_in[20];
  const float* pair_rp  = (const float*)d_in[21];
  const float* cls_w1   = (const float*)d_in[22];
  const float* cls_b1   = (const float*)d_in[23];
  const float* cls_w2   = (const float*)d_in[24];
  const float* cls_b2   = (const float*)d_in[25];
  float* out = (float*)d_out;

  char* ws = (char*)d_ws;
  float* xb0 = (float*)(ws + 0);
  float* xb1 = (float*)(ws + 786432);
  float* qb[2] = { (float*)(ws + 1572864), (float*)(ws + 3932160) };
  float* kb[2] = { (float*)(ws + 2359296), (float*)(ws + 4718592) };
  float* vb[2] = { (float*)(ws + 3145728), (float*)(ws + 5505024) };
  float* o   = (float*)(ws + 6291456);
  float* f1  = (float*)(ws + 7077888);
  float* pq  = (float*)(ws + 10223616);
  float* pk  = (float*)(ws + 11010048);
  float* RB  = (float*)(ws + 11796480);
  unsigned short* W1p = (unsigned short*)(ws + 13369344);
  float* abias = (float*)(ws + 13500416);
  unsigned* cnt = (unsigned*)(ws + 13549568);

  (void)in_sizes; (void)n_in; (void)out_size; (void)ws_size;

  hipFuncSetAttribute(reinterpret_cast<const void*>(k_pair),
                      hipFuncAttributeMaxDynamicSharedMemorySize, PAIR_SMEM);

  hipMemsetAsync((void*)cnt, 0, NLAYER * 64 * sizeof(unsigned), stream);

  k_prep<<<502, 256, 0, stream>>>(seq, tok_emb, rp_emb, wq, wk, wv,
                                  ln1_s, ln1_b, pair_rp, cls_w1, cls_b1,
                                  xb0, qb[0], kb[0], vb[0], RB, W1p, abias);

  for (int l = 0; l < NLAYER; ++l) {
    LArgs a{};
    int pi = l & 1, po = pi ^ 1;
    a.qin = qb[pi]; a.kin = kb[pi]; a.vin = vb[pi];
    a.xin = (l & 1) ? xb1 : xb0;
    a.xout = (l & 1) ? xb0 : xb1;
    a.abias = abias; a.o = o; a.f1 = f1;
    a.wo   = wo + (size_t)l * DM * DM;
    a.ln2s = ln2_s + l * DM; a.ln2b = ln2_b + l * DM;
    a.fw1 = ffn_w1 + (size_t)l * DM * DFF; a.fb1 = ffn_b1 + (size_t)l * DFF;
    a.fw2 = ffn_w2 + (size_t)l * DFF * DM; a.fb2 = ffn_b2 + (size_t)l * DM;
    a.cnt = cnt + l * 64;
    a.last = (l == NLAYER - 1);
    if (!a.last) {
      a.wnq = wq + (size_t)(l + 1) * DM * DM;
      a.wnk = wk + (size_t)(l + 1) * DM * DM;
      a.wnv = wv + (size_t)(l + 1) * DM * DM;
      a.lnns = ln1_s + (l + 1) * DM; a.lnnb = ln1_b + (l + 1) * DM;
      a.qout = qb[po]; a.kout = kb[po]; a.vout = vb[po];
      a.nqb = nullptr; a.nkb = nullptr;
    } else {
      a.wnq = pair_q_w; a.wnk = pair_k_w;
      a.wnv = nullptr;
      a.lnns = lnf_s; a.lnnb = lnf_b;
      a.qout = pq; a.kout = pk; a.vout = nullptr;
      a.nqb = pair_q_b; a.nkb = pair_k_b;
    }
    k_layer<<<396, 256, 0, stream>>>(a);
  }

  k_pair<<<dim3(24, 192), 256, PAIR_SMEM, stream>>>(pq, pk, W1p, RB, cls_w2, cls_b2, out);
}

// Round 7
// 1724.322 us; speedup vs baseline: 1.9077x; 1.9077x over previous
//
#include <hip/hip_runtime.h>
#include <hip/hip_bf16.h>
#include <stdint.h>

// ---------------------------------------------------------------------------
#define LSEQ 768
#define DM   256
#define NH   8
#define DK   32
#define DFF  1024
#define NLAYER 8
#define NDD  1535
// ---------------------------------------------------------------------------

typedef __attribute__((ext_vector_type(8))) short  bf16x8;
typedef __attribute__((ext_vector_type(4))) float  f32x4;

__device__ __forceinline__ unsigned short f2bf(float f) {
  unsigned u = __float_as_uint(f);
  u += 0x7fffu + ((u >> 16) & 1u);       // RNE
  return (unsigned short)(u >> 16);
}
__device__ __forceinline__ unsigned pk2(float a, float b) {
  __hip_bfloat162 h = __float22bfloat162_rn(make_float2(a, b));
  union { __hip_bfloat162 h; unsigned u; } c; c.h = h;
  return c.u;
}
__device__ __forceinline__ int bucket_of(int dd) {
  int rel = dd - 767;
  int ret = rel < 0 ? 32 : 0;
  int arp = rel < 0 ? -rel : rel;
  if (arp < 16) return ret + arp;
  const float lr = 2.772588722239781f;   // float(np.log(16))
  float val = logf((float)arp * 0.0625f) / lr * 16.0f;
  int vi = 16 + (int)val;
  return ret + (vi < 31 ? vi : 31);
}

// ---------------------------------------------------------------------------
// Legacy 64x64 GEMM tile (k_prep only; plain caching, gather variants).
// LDS from smc: As 2x32x68 @0, Bs @17408, stat @34816, red @35328 -> 37376.
template <int LN, int GR>
__device__ void gemm_tile(const float* gsrc, const int* seqIdx,
                          const float* B, const float* bias, float* C,
                          const float* lns, const float* lnb,
                          int M, int K, int N, int m0, int n0, char* smc) {
  float (*As)[32][68] = (float (*)[32][68])smc;
  float (*Bs)[32][68] = (float (*)[32][68])(smc + 17408);
  float (*stat)[2]    = (float (*)[2])(smc + 34816);
  float (*red)[8]     = (float (*)[8])(smc + 35328);

  int t = threadIdx.x;
  int arow = t >> 2, akq = (t & 3) * 8;
  int mg = m0 + arow;
  int mgc = mg < M ? mg : M - 1;
  const float* Ar = (GR == 1) ? (gsrc + (size_t)seqIdx[mgc] * K)
                              : (gsrc + (size_t)bucket_of(mgc) * K);
  float mean = 0.f, rstd = 0.f;
  if (LN) {
    int lq = t & 3;
    float s = 0.f, s2 = 0.f;
    const float* p = Ar + lq * 64;
    #pragma unroll
    for (int c = 0; c < 64; c += 4) {
      float4 v = *(const float4*)(p + c);
      s  += v.x + v.y + v.z + v.w;
      s2 += v.x * v.x + v.y * v.y + v.z * v.z + v.w * v.w;
    }
    red[arow][lq] = s; red[arow][lq + 4] = s2;
    __syncthreads();
    if (lq == 0) {
      float sm = red[arow][0] + red[arow][1] + red[arow][2] + red[arow][3];
      float sq = red[arow][4] + red[arow][5] + red[arow][6] + red[arow][7];
      float m = sm * (1.f / 256.f);
      float v = sq * (1.f / 256.f) - m * m;
      stat[arow][0] = m;
      stat[arow][1] = rsqrtf(v + 1e-5f);
    }
    __syncthreads();
    mean = stat[arow][0]; rstd = stat[arow][1];
  }

  int bkr = t >> 3, bn8 = (t & 7) * 8;
  int ty = t >> 4, tx = t & 15;
  float acc[4][4] = {};
  int nk = K >> 5;

  for (int kt = 0; kt < nk; ++kt) {
    int k0 = kt << 5;
    float4 a0 = *(const float4*)(Ar + k0 + akq);
    float4 a1 = *(const float4*)(Ar + k0 + akq + 4);
    if (LN) {
      float4 ls0 = *(const float4*)(lns + k0 + akq), ls1 = *(const float4*)(lns + k0 + akq + 4);
      float4 lb0 = *(const float4*)(lnb + k0 + akq), lb1 = *(const float4*)(lnb + k0 + akq + 4);
      a0.x=(a0.x-mean)*rstd*ls0.x+lb0.x; a0.y=(a0.y-mean)*rstd*ls0.y+lb0.y;
      a0.z=(a0.z-mean)*rstd*ls0.z+lb0.z; a0.w=(a0.w-mean)*rstd*ls0.w+lb0.w;
      a1.x=(a1.x-mean)*rstd*ls1.x+lb1.x; a1.y=(a1.y-mean)*rstd*ls1.y+lb1.y;
      a1.z=(a1.z-mean)*rstd*ls1.z+lb1.z; a1.w=(a1.w-mean)*rstd*ls1.w+lb1.w;
    }
    int cur = kt & 1;
    As[cur][akq+0][arow]=a0.x; As[cur][akq+1][arow]=a0.y; As[cur][akq+2][arow]=a0.z; As[cur][akq+3][arow]=a0.w;
    As[cur][akq+4][arow]=a1.x; As[cur][akq+5][arow]=a1.y; As[cur][akq+6][arow]=a1.z; As[cur][akq+7][arow]=a1.w;
    *(float4*)&Bs[cur][bkr][bn8] = *(const float4*)(B + (size_t)(k0 + bkr) * N + n0 + bn8);
    *(float4*)&Bs[cur][bkr][bn8+4] = *(const float4*)(B + (size_t)(k0 + bkr) * N + n0 + bn8 + 4);
    __syncthreads();
    #pragma unroll 8
    for (int kk = 0; kk < 32; ++kk) {
      float4 a = *(float4*)&As[cur][kk][ty * 4];
      float4 b = *(float4*)&Bs[cur][kk][tx * 4];
      acc[0][0]=fmaf(a.x,b.x,acc[0][0]); acc[0][1]=fmaf(a.x,b.y,acc[0][1]);
      acc[0][2]=fmaf(a.x,b.z,acc[0][2]); acc[0][3]=fmaf(a.x,b.w,acc[0][3]);
      acc[1][0]=fmaf(a.y,b.x,acc[1][0]); acc[1][1]=fmaf(a.y,b.y,acc[1][1]);
      acc[1][2]=fmaf(a.y,b.z,acc[1][2]); acc[1][3]=fmaf(a.y,b.w,acc[1][3]);
      acc[2][0]=fmaf(a.z,b.x,acc[2][0]); acc[2][1]=fmaf(a.z,b.y,acc[2][1]);
      acc[2][2]=fmaf(a.z,b.z,acc[2][2]); acc[2][3]=fmaf(a.z,b.w,acc[2][3]);
      acc[3][0]=fmaf(a.w,b.x,acc[3][0]); acc[3][1]=fmaf(a.w,b.y,acc[3][1]);
      acc[3][2]=fmaf(a.w,b.z,acc[3][2]); acc[3][3]=fmaf(a.w,b.w,acc[3][3]);
    }
    __syncthreads();
  }

  #pragma unroll
  for (int u = 0; u < 4; ++u) {
    int m = m0 + ty * 4 + u;
    if (m < M) {
      int n = n0 + tx * 4;
      float4 val = make_float4(acc[u][0], acc[u][1], acc[u][2], acc[u][3]);
      if (bias) {
        float4 bv = *(const float4*)(bias + n);
        val.x += bv.x; val.y += bv.y; val.z += bv.z; val.w += bv.w;
      }
      *(float4*)(C + (size_t)m * N + n) = val;
    }
  }
}

// ---------------------------------------------------------------------------
// Prep: RB gemm + qkv layer0 + embed + abias + W1p pack. One dispatch.
__global__ __launch_bounds__(256, 2) void k_prep(
    const int* __restrict__ seq, const float* __restrict__ tok_emb,
    const float* __restrict__ rp_emb,
    const float* __restrict__ wq0, const float* __restrict__ wk0,
    const float* __restrict__ wv0,
    const float* __restrict__ ln1s0, const float* __restrict__ ln1b0,
    const float* __restrict__ pair_rp, const float* __restrict__ cls_w1,
    const float* __restrict__ cls_b1,
    float* x0, float* q0, float* k0, float* v0, float* RB,
    unsigned short* W1p, float* abias) {
  __shared__ __align__(16) char sm[37376];
  int b = blockIdx.x, t = threadIdx.x;
  if (b < 96) {
    int m0 = (b % 24) * 64, n0 = (b / 24) * 64;
    gemm_tile<0,2>(pair_rp, nullptr, cls_w1, cls_b1, RB,
                   nullptr, nullptr, NDD, 256, 256, m0, n0, sm);
  } else if (b < 240) {
    int u = b - 96;
    int n0g = (u % 12) * 64, m0 = (u / 12) * 64;
    int bi = n0g >> 8, n0 = n0g & 255;
    const float* B = bi == 0 ? wq0 : (bi == 1 ? wk0 : wv0);
    float* C = bi == 0 ? q0 : (bi == 1 ? k0 : v0);
    gemm_tile<1,1>(tok_emb, seq, B, nullptr, C,
                   ln1s0, ln1b0, LSEQ, 256, 256, m0, n0, sm);
  } else if (b < 432) {
    int row = (b - 240) * 4 + (t >> 6), c = (t & 63) * 4;
    *(float4*)(x0 + (size_t)row * DM + c) =
        *(const float4*)(tok_emb + (size_t)seq[row] * DM + c);
  } else if (b < 438) {
    int dd = (b - 432) * 256 + t;
    if (dd < NDD) {
      int bk = bucket_of(dd);
      #pragma unroll
      for (int h = 0; h < NH; ++h) abias[dd * 8 + h] = rp_emb[bk * 8 + h];
    }
  } else {
    int base = (b - 438) * 1024 + t * 4;
    #pragma unroll
    for (int uu = 0; uu < 4; ++uu) {
      int id = base + uu;
      int e = id & 7, lane = (id >> 3) & 63, g = (id >> 9) & 15, kc = id >> 13;
      int kg = kc * 32 + (lane >> 4) * 8 + e;
      int n  = g * 16 + (lane & 15);
      W1p[id] = f2bf(cls_w1[(size_t)kg * 256 + n]);
    }
  }
}

// ---------------------------------------------------------------------------
// Main GEMM: 64 rows x 128 cols per block, 256 threads, 4x8 thread tile
// (12 LDS floats / 32 fma), BK=32 register-prefetch double-buffered LDS.
// All memory plain (cross-dispatch sync via kernel boundary).
// ATOMIC variant: split-K over blockIdx.z (segments of g.K), atomicAdd into C.
struct GA {
  const float* A;
  const float* B0; const float* B1; const float* B2;
  const float* bias0; const float* bias1; const float* bias2;
  float* C0; float* C1; float* C2;
  const float* res; const float* lns; const float* lnb;
  int K, Nper, ldA, ntile;
};

template <int LN, int GELU, int RES, int ATOMIC>
__global__ __launch_bounds__(256) void k_gemm(GA g) {
  __shared__ float As[2][32][68];
  __shared__ float Bs[2][32][132];
  __shared__ float stat[64][2];
  __shared__ float red[64][8];

  int t = threadIdx.x;
  int bi = blockIdx.x / g.ntile, nt = blockIdx.x % g.ntile;
  int n0 = nt * 128;
  int m0 = blockIdx.y * 64;
  const float* A = g.A;
  const float* B = bi == 0 ? g.B0 : (bi == 1 ? g.B1 : g.B2);
  const float* bias = bi == 0 ? g.bias0 : (bi == 1 ? g.bias1 : g.bias2);
  float* C = bi == 0 ? g.C0 : (bi == 1 ? g.C1 : g.C2);
  int K = g.K;
  if (ATOMIC) {
    int ks = blockIdx.z;
    A += (size_t)ks * K;
    B += (size_t)ks * K * g.Nper;
    if (ks) bias = nullptr;
  }

  int arow = t >> 2, akq = (t & 3) * 8;
  const float* Ar = A + (size_t)(m0 + arow) * g.ldA;

  float mean = 0.f, rstd = 0.f;
  if (LN) {
    int lq = t & 3;
    float s = 0.f, s2 = 0.f;
    const float* p = Ar + lq * 64;
    #pragma unroll
    for (int c = 0; c < 64; c += 4) {
      float4 v = *(const float4*)(p + c);
      s  += v.x + v.y + v.z + v.w;
      s2 += v.x * v.x + v.y * v.y + v.z * v.z + v.w * v.w;
    }
    red[arow][lq] = s; red[arow][lq + 4] = s2;
    __syncthreads();
    if (lq == 0) {
      float sm = red[arow][0] + red[arow][1] + red[arow][2] + red[arow][3];
      float sq = red[arow][4] + red[arow][5] + red[arow][6] + red[arow][7];
      float m = sm * (1.f / 256.f);
      float v = sq * (1.f / 256.f) - m * m;
      stat[arow][0] = m;
      stat[arow][1] = rsqrtf(v + 1e-5f);
    }
    __syncthreads();
    mean = stat[arow][0]; rstd = stat[arow][1];
  }

  int bkr = t >> 3, bcol = (t & 7) * 16;
  int ty = t >> 4, tx = t & 15;
  float acc[4][8] = {};
  int nk = K >> 5;
  float4 pa0, pa1, pb0, pb1, pb2, pb3;

  {  // prologue: chunk 0 -> buf 0
    pa0 = *(const float4*)(Ar + akq);
    pa1 = *(const float4*)(Ar + akq + 4);
    if (LN) {
      float4 ls0 = *(const float4*)(g.lns + akq), ls1 = *(const float4*)(g.lns + akq + 4);
      float4 lb0 = *(const float4*)(g.lnb + akq), lb1 = *(const float4*)(g.lnb + akq + 4);
      pa0.x=(pa0.x-mean)*rstd*ls0.x+lb0.x; pa0.y=(pa0.y-mean)*rstd*ls0.y+lb0.y;
      pa0.z=(pa0.z-mean)*rstd*ls0.z+lb0.z; pa0.w=(pa0.w-mean)*rstd*ls0.w+lb0.w;
      pa1.x=(pa1.x-mean)*rstd*ls1.x+lb1.x; pa1.y=(pa1.y-mean)*rstd*ls1.y+lb1.y;
      pa1.z=(pa1.z-mean)*rstd*ls1.z+lb1.z; pa1.w=(pa1.w-mean)*rstd*ls1.w+lb1.w;
    }
    const float* Bp = B + (size_t)bkr * g.Nper + n0 + bcol;
    pb0 = *(const float4*)(Bp);      pb1 = *(const float4*)(Bp + 4);
    pb2 = *(const float4*)(Bp + 8);  pb3 = *(const float4*)(Bp + 12);
    As[0][akq+0][arow]=pa0.x; As[0][akq+1][arow]=pa0.y; As[0][akq+2][arow]=pa0.z; As[0][akq+3][arow]=pa0.w;
    As[0][akq+4][arow]=pa1.x; As[0][akq+5][arow]=pa1.y; As[0][akq+6][arow]=pa1.z; As[0][akq+7][arow]=pa1.w;
    *(float4*)&Bs[0][bkr][bcol]    = pb0;
    *(float4*)&Bs[0][bkr][bcol+4]  = pb1;
    *(float4*)&Bs[0][bkr][bcol+8]  = pb2;
    *(float4*)&Bs[0][bkr][bcol+12] = pb3;
  }
  __syncthreads();

  for (int kt = 0; kt < nk; ++kt) {
    int cur = kt & 1;
    if (kt + 1 < nk) {
      int k0 = (kt + 1) << 5;
      pa0 = *(const float4*)(Ar + k0 + akq);
      pa1 = *(const float4*)(Ar + k0 + akq + 4);
      if (LN) {
        float4 ls0 = *(const float4*)(g.lns + k0 + akq), ls1 = *(const float4*)(g.lns + k0 + akq + 4);
        float4 lb0 = *(const float4*)(g.lnb + k0 + akq), lb1 = *(const float4*)(g.lnb + k0 + akq + 4);
        pa0.x=(pa0.x-mean)*rstd*ls0.x+lb0.x; pa0.y=(pa0.y-mean)*rstd*ls0.y+lb0.y;
        pa0.z=(pa0.z-mean)*rstd*ls0.z+lb0.z; pa0.w=(pa0.w-mean)*rstd*ls0.w+lb0.w;
        pa1.x=(pa1.x-mean)*rstd*ls1.x+lb1.x; pa1.y=(pa1.y-mean)*rstd*ls1.y+lb1.y;
        pa1.z=(pa1.z-mean)*rstd*ls1.z+lb1.z; pa1.w=(pa1.w-mean)*rstd*ls1.w+lb1.w;
      }
      const float* Bp = B + (size_t)(k0 + bkr) * g.Nper + n0 + bcol;
      pb0 = *(const float4*)(Bp);      pb1 = *(const float4*)(Bp + 4);
      pb2 = *(const float4*)(Bp + 8);  pb3 = *(const float4*)(Bp + 12);
    }
    #pragma unroll
    for (int kk = 0; kk < 32; ++kk) {
      float4 a  = *(float4*)&As[cur][kk][ty * 4];
      float4 b0 = *(float4*)&Bs[cur][kk][tx * 8];
      float4 b1 = *(float4*)&Bs[cur][kk][tx * 8 + 4];
      acc[0][0]=fmaf(a.x,b0.x,acc[0][0]); acc[0][1]=fmaf(a.x,b0.y,acc[0][1]);
      acc[0][2]=fmaf(a.x,b0.z,acc[0][2]); acc[0][3]=fmaf(a.x,b0.w,acc[0][3]);
      acc[0][4]=fmaf(a.x,b1.x,acc[0][4]); acc[0][5]=fmaf(a.x,b1.y,acc[0][5]);
      acc[0][6]=fmaf(a.x,b1.z,acc[0][6]); acc[0][7]=fmaf(a.x,b1.w,acc[0][7]);
      acc[1][0]=fmaf(a.y,b0.x,acc[1][0]); acc[1][1]=fmaf(a.y,b0.y,acc[1][1]);
      acc[1][2]=fmaf(a.y,b0.z,acc[1][2]); acc[1][3]=fmaf(a.y,b0.w,acc[1][3]);
      acc[1][4]=fmaf(a.y,b1.x,acc[1][4]); acc[1][5]=fmaf(a.y,b1.y,acc[1][5]);
      acc[1][6]=fmaf(a.y,b1.z,acc[1][6]); acc[1][7]=fmaf(a.y,b1.w,acc[1][7]);
      acc[2][0]=fmaf(a.z,b0.x,acc[2][0]); acc[2][1]=fmaf(a.z,b0.y,acc[2][1]);
      acc[2][2]=fmaf(a.z,b0.z,acc[2][2]); acc[2][3]=fmaf(a.z,b0.w,acc[2][3]);
      acc[2][4]=fmaf(a.z,b1.x,acc[2][4]); acc[2][5]=fmaf(a.z,b1.y,acc[2][5]);
      acc[2][6]=fmaf(a.z,b1.z,acc[2][6]); acc[2][7]=fmaf(a.z,b1.w,acc[2][7]);
      acc[3][0]=fmaf(a.w,b0.x,acc[3][0]); acc[3][1]=fmaf(a.w,b0.y,acc[3][1]);
      acc[3][2]=fmaf(a.w,b0.z,acc[3][2]); acc[3][3]=fmaf(a.w,b0.w,acc[3][3]);
      acc[3][4]=fmaf(a.w,b1.x,acc[3][4]); acc[3][5]=fmaf(a.w,b1.y,acc[3][5]);
      acc[3][6]=fmaf(a.w,b1.z,acc[3][6]); acc[3][7]=fmaf(a.w,b1.w,acc[3][7]);
    }
    if (kt + 1 < nk) {
      int nxt = cur ^ 1;
      As[nxt][akq+0][arow]=pa0.x; As[nxt][akq+1][arow]=pa0.y; As[nxt][akq+2][arow]=pa0.z; As[nxt][akq+3][arow]=pa0.w;
      As[nxt][akq+4][arow]=pa1.x; As[nxt][akq+5][arow]=pa1.y; As[nxt][akq+6][arow]=pa1.z; As[nxt][akq+7][arow]=pa1.w;
      *(float4*)&Bs[nxt][bkr][bcol]    = pb0;
      *(float4*)&Bs[nxt][bkr][bcol+4]  = pb1;
      *(float4*)&Bs[nxt][bkr][bcol+8]  = pb2;
      *(float4*)&Bs[nxt][bkr][bcol+12] = pb3;
    }
    __syncthreads();
  }

  #pragma unroll
  for (int u = 0; u < 4; ++u) {
    int m = m0 + ty * 4 + u;
    #pragma unroll
    for (int vq = 0; vq < 2; ++vq) {
      int n = n0 + tx * 8 + vq * 4;
      float4 val = make_float4(acc[u][vq*4+0], acc[u][vq*4+1],
                               acc[u][vq*4+2], acc[u][vq*4+3]);
      if (bias) {
        float4 bv = *(const float4*)(bias + n);
        val.x += bv.x; val.y += bv.y; val.z += bv.z; val.w += bv.w;
      }
      if (GELU) {
        val.x = 0.5f * val.x * (1.f + erff(val.x * 0.70710678118654752f));
        val.y = 0.5f * val.y * (1.f + erff(val.y * 0.70710678118654752f));
        val.z = 0.5f * val.z * (1.f + erff(val.z * 0.70710678118654752f));
        val.w = 0.5f * val.w * (1.f + erff(val.w * 0.70710678118654752f));
      }
      if (RES) {
        float4 r = *(const float4*)(g.res + (size_t)m * g.Nper + n);
        val.x += r.x; val.y += r.y; val.z += r.z; val.w += r.w;
      }
      if (ATOMIC) {
        atomicAdd(&C[(size_t)m * g.Nper + n + 0], val.x);
        atomicAdd(&C[(size_t)m * g.Nper + n + 1], val.y);
        atomicAdd(&C[(size_t)m * g.Nper + n + 2], val.z);
        atomicAdd(&C[(size_t)m * g.Nper + n + 3], val.w);
      } else {
        *(float4*)(C + (size_t)m * g.Nper + n) = val;
      }
    }
  }
}

// ---------------------------------------------------------------------------
// Attention v2: 16 q-rows x 1 head per block, 256 thr, 2 blocks/CU.
// k/v staged TRANSPOSED into LDS per 128-key chunk (coalesced global reads,
// conflict-free b128 compute reads). All global traffic plain (cross-dispatch).
// LDS map (bytes): S[16][776]@0 (49664) | KV[32][132]@49664 (16896, reused as
// part[4096]) | QS[16][33]@66560 (2112) | BS[784]@68672 (3136) |
// red[16][16]@71808 (1024) | mrow@72832 | linv@72896  -> 72960 total.
#define ATTN_SMEM 72960

__global__ __launch_bounds__(256, 2) void k_attn2(
    const float* __restrict__ q, const float* __restrict__ k,
    const float* __restrict__ v, const float* __restrict__ abias,
    float* __restrict__ o) {
  extern __shared__ char sm[];
  float* S  = (float*)sm;
  float* KV = (float*)(sm + 49664);
  float* QS = (float*)(sm + 66560);
  float* BS = (float*)(sm + 68672);
  float (*red)[16] = (float (*)[16])(sm + 71808);
  float* mrow = (float*)(sm + 72832);
  float* linv = (float*)(sm + 72896);

  int i0 = blockIdx.x * 16, h = blockIdx.y, hc = h * DK;
  int t = threadIdx.x;

  for (int u = t; u < 783; u += 256)
    BS[u] = abias[(size_t)(i0 + u) * 8 + h];
  {
    int r = t >> 4, c = t & 15;
    const float inv = 0.17677669529663687f;   // 1/sqrt(32)
    QS[r * 33 + c]      = q[(size_t)(i0 + r) * DM + hc + c] * inv;
    QS[r * 33 + c + 16] = q[(size_t)(i0 + r) * DM + hc + c + 16] * inv;
  }

  int kx = t & 31, ry = t >> 5;
  int key = t >> 1, half = t & 1;

  // ---- QK phase ----
  for (int cc = 0; cc < 6; ++cc) {
    const float* kp = k + (size_t)(cc * 128 + key) * DM + hc + half * 16;
    float4 L0 = *(const float4*)(kp);
    float4 L1 = *(const float4*)(kp + 4);
    float4 L2 = *(const float4*)(kp + 8);
    float4 L3 = *(const float4*)(kp + 12);
    __syncthreads();                      // prior chunk consumed (covers QS/BS at cc=0)
    int cb = half * 16;
    KV[(cb+ 0)*132+key]=L0.x; KV[(cb+ 1)*132+key]=L0.y; KV[(cb+ 2)*132+key]=L0.z; KV[(cb+ 3)*132+key]=L0.w;
    KV[(cb+ 4)*132+key]=L1.x; KV[(cb+ 5)*132+key]=L1.y; KV[(cb+ 6)*132+key]=L1.z; KV[(cb+ 7)*132+key]=L1.w;
    KV[(cb+ 8)*132+key]=L2.x; KV[(cb+ 9)*132+key]=L2.y; KV[(cb+10)*132+key]=L2.z; KV[(cb+11)*132+key]=L2.w;
    KV[(cb+12)*132+key]=L3.x; KV[(cb+13)*132+key]=L3.y; KV[(cb+14)*132+key]=L3.z; KV[(cb+15)*132+key]=L3.w;
    __syncthreads();

    float s0x=0,s0y=0,s0z=0,s0w=0, s1x=0,s1y=0,s1z=0,s1w=0;
    #pragma unroll
    for (int kk = 0; kk < 32; ++kk) {
      float q0 = QS[(ry*2    )*33 + kk];
      float q1 = QS[(ry*2 + 1)*33 + kk];
      float4 kv4 = *(const float4*)&KV[kk*132 + kx*4];
      s0x = fmaf(q0, kv4.x, s0x); s0y = fmaf(q0, kv4.y, s0y);
      s0z = fmaf(q0, kv4.z, s0z); s0w = fmaf(q0, kv4.w, s0w);
      s1x = fmaf(q1, kv4.x, s1x); s1y = fmaf(q1, kv4.y, s1y);
      s1z = fmaf(q1, kv4.z, s1z); s1w = fmaf(q1, kv4.w, s1w);
    }
    int jb = cc * 128 + kx * 4;
    int r0 = ry * 2, r1 = r0 + 1;
    S[r0*776 + jb+0] = s0x + BS[r0 + 767 - (jb+0)];
    S[r0*776 + jb+1] = s0y + BS[r0 + 767 - (jb+1)];
    S[r0*776 + jb+2] = s0z + BS[r0 + 767 - (jb+2)];
    S[r0*776 + jb+3] = s0w + BS[r0 + 767 - (jb+3)];
    S[r1*776 + jb+0] = s1x + BS[r1 + 767 - (jb+0)];
    S[r1*776 + jb+1] = s1y + BS[r1 + 767 - (jb+1)];
    S[r1*776 + jb+2] = s1z + BS[r1 + 767 - (jb+2)];
    S[r1*776 + jb+3] = s1w + BS[r1 + 767 - (jb+3)];
  }
  __syncthreads();

  // ---- softmax (rescan) ----
  {
    int ti = t >> 4, tj = t & 15;
    float mx = -1e30f;
    for (int jc = 0; jc < 48; ++jc)
      mx = fmaxf(mx, S[ti*776 + jc*16 + tj]);
    red[ti][tj] = mx;
    __syncthreads();
    if (tj == 0) {
      float m2 = red[ti][0];
      #pragma unroll
      for (int u = 1; u < 16; ++u) m2 = fmaxf(m2, red[ti][u]);
      mrow[ti] = m2;
    }
    __syncthreads();
    float m2 = mrow[ti];
    float sum = 0.f;
    for (int jc = 0; jc < 48; ++jc) {
      int j = jc*16 + tj;
      float e = __expf(S[ti*776 + j] - m2);
      S[ti*776 + j] = e;
      sum += e;
    }
    red[ti][tj] = sum;
    __syncthreads();
    if (tj == 0) {
      float s2 = 0.f;
      #pragma unroll
      for (int u = 0; u < 16; ++u) s2 += red[ti][u];
      linv[ti] = 1.f / s2;
    }
  }

  // ---- PV phase ----
  int cp = t & 15, jg = t >> 4;
  int c0 = cp * 2, c1 = c0 + 1;
  float oc0[16] = {}, oc1[16] = {};
  for (int cc = 0; cc < 6; ++cc) {
    const float* vp = v + (size_t)(cc * 128 + key) * DM + hc + half * 16;
    float4 L0 = *(const float4*)(vp);
    float4 L1 = *(const float4*)(vp + 4);
    float4 L2 = *(const float4*)(vp + 8);
    float4 L3 = *(const float4*)(vp + 12);
    __syncthreads();                      // prior chunk consumed / softmax done
    int cb = half * 16;
    KV[(cb+ 0)*132+key]=L0.x; KV[(cb+ 1)*132+key]=L0.y; KV[(cb+ 2)*132+key]=L0.z; KV[(cb+ 3)*132+key]=L0.w;
    KV[(cb+ 4)*132+key]=L1.x; KV[(cb+ 5)*132+key]=L1.y; KV[(cb+ 6)*132+key]=L1.z; KV[(cb+ 7)*132+key]=L1.w;
    KV[(cb+ 8)*132+key]=L2.x; KV[(cb+ 9)*132+key]=L2.y; KV[(cb+10)*132+key]=L2.z; KV[(cb+11)*132+key]=L2.w;
    KV[(cb+12)*132+key]=L3.x; KV[(cb+13)*132+key]=L3.y; KV[(cb+14)*132+key]=L3.z; KV[(cb+15)*132+key]=L3.w;
    __syncthreads();

    #pragma unroll
    for (int jj2 = 0; jj2 < 2; ++jj2) {
      int jb = jg * 8 + jj2 * 4;
      float4 vA = *(const float4*)&KV[c0*132 + jb];
      float4 vB = *(const float4*)&KV[c1*132 + jb];
      #pragma unroll
      for (int r = 0; r < 16; ++r) {
        float4 sv = *(const float4*)&S[r*776 + cc*128 + jb];
        oc0[r] += sv.x*vA.x + sv.y*vA.y + sv.z*vA.z + sv.w*vA.w;
        oc1[r] += sv.x*vB.x + sv.y*vB.y + sv.z*vB.z + sv.w*vB.w;
      }
    }
  }

  // ---- reduce over jg (two row-halves through KV region) + store ----
  #pragma unroll
  for (int h2 = 0; h2 < 2; ++h2) {
    __syncthreads();
    #pragma unroll
    for (int r = 0; r < 8; ++r) {
      KV[(jg*8 + r)*32 + c0] = oc0[h2*8 + r];
      KV[(jg*8 + r)*32 + c1] = oc1[h2*8 + r];
    }
    __syncthreads();
    int r = t >> 5, c = t & 31;
    float s = 0.f;
    #pragma unroll
    for (int jgg = 0; jgg < 16; ++jgg) s += KV[(jgg*8 + r)*32 + c];
    o[(size_t)(i0 + h2*8 + r) * DM + hc + c] = s * linv[h2*8 + r];
  }
}

// ---------------------------------------------------------------------------
// Fused pair head (round-5, validated): LDS-staged q/k, W1p reg-prefetch.
#define PAIR_SMEM 74864

__global__ __launch_bounds__(256, 2) void k_pair(
    const float* __restrict__ pq, const float* __restrict__ pk,
    const unsigned short* __restrict__ W1p, const float* __restrict__ RB,
    const float* __restrict__ w2, const float* __restrict__ b2,
    float* __restrict__ out) {
  extern __shared__ char smem[];
  float* qs   = (float*)smem;
  float* ks   = (float*)(smem + 4160);
  float* RB_s = (float*)(smem + 37440);
  float* racc = (float*)(smem + 73840);

  int t = threadIdx.x;
  int j0 = blockIdx.x * 32;
  int i0 = blockIdx.y * 4;
  int w = t >> 6, l = t & 63;
  int q4 = l >> 4, l15 = l & 15;
  int mwv = w & 1, nwv = w >> 1;

  {
    int row = t >> 6, c4 = (t & 63) * 4;
    *(float4*)(qs + row * 260 + c4) = *(const float4*)(pq + (size_t)(i0 + row) * DM + c4);
    #pragma unroll
    for (int r8 = 0; r8 < 8; ++r8) {
      int idx = t + r8 * 256;
      int kr = idx >> 6, kc4 = (idx & 63) * 4;
      *(float4*)(ks + kr * 260 + kc4) = *(const float4*)(pk + (size_t)(j0 + kr) * DM + kc4);
    }
    int ddmin = i0 - j0 + 736;
    for (int idx = t; idx < 35 * 64; idx += 256) {
      int lc = idx >> 6, c4b = (idx & 63) * 4;
      *(float4*)(RB_s + lc * 260 + c4b) =
          *(const float4*)(RB + (size_t)(ddmin + lc) * 256 + c4b);
    }
    racc[t] = 0.f;
  }
  __syncthreads();

  const unsigned short* Bp = W1p + (size_t)(nwv * 8) * 512 + (size_t)l * 8;
  const float* q0p = qs + (mwv * 2) * 260;
  const float* q1p = qs + (mwv * 2 + 1) * 260;
  const float* k0p = ks + l15 * 260;
  const float* k1p = ks + (16 + l15) * 260;

  f32x4 acc[4][8];
  #pragma unroll
  for (int aa = 0; aa < 4; ++aa)
    #pragma unroll
    for (int bb = 0; bb < 8; ++bb) acc[aa][bb] = (f32x4){0.f, 0.f, 0.f, 0.f};

  bf16x8 bcur[8];
  #pragma unroll
  for (int nt = 0; nt < 8; ++nt) bcur[nt] = *(const bf16x8*)(Bp + nt * 512);

  for (int kc = 0; kc < 8; ++kc) {
    bf16x8 bnxt[8];
    if (kc < 7) {
      const unsigned short* bbn = Bp + (size_t)(kc + 1) * 8192;
      #pragma unroll
      for (int nt = 0; nt < 8; ++nt) bnxt[nt] = *(const bf16x8*)(bbn + nt * 512);
    }
    int c = kc * 32 + q4 * 8;
    float4 qa0 = *(const float4*)(q0p + c), qa1 = *(const float4*)(q0p + c + 4);
    float4 qb0 = *(const float4*)(q1p + c), qb1 = *(const float4*)(q1p + c + 4);
    float4 ka0 = *(const float4*)(k0p + c), ka1 = *(const float4*)(k0p + c + 4);
    float4 kb0 = *(const float4*)(k1p + c), kb1 = *(const float4*)(k1p + c + 4);

    union { bf16x8 v; unsigned u[4]; } af[4];
    af[0].u[0] = pk2(qa0.x*ka0.x, qa0.y*ka0.y); af[0].u[1] = pk2(qa0.z*ka0.z, qa0.w*ka0.w);
    af[0].u[2] = pk2(qa1.x*ka1.x, qa1.y*ka1.y); af[0].u[3] = pk2(qa1.z*ka1.z, qa1.w*ka1.w);
    af[1].u[0] = pk2(qa0.x*kb0.x, qa0.y*kb0.y); af[1].u[1] = pk2(qa0.z*kb0.z, qa0.w*kb0.w);
    af[1].u[2] = pk2(qa1.x*kb1.x, qa1.y*kb1.y); af[1].u[3] = pk2(qa1.z*kb1.z, qa1.w*kb1.w);
    af[2].u[0] = pk2(qb0.x*ka0.x, qb0.y*ka0.y); af[2].u[1] = pk2(qb0.z*ka0.z, qb0.w*ka0.w);
    af[2].u[2] = pk2(qb1.x*ka1.x, qb1.y*ka1.y); af[2].u[3] = pk2(qb1.z*ka1.z, qb1.w*ka1.w);
    af[3].u[0] = pk2(qb0.x*kb0.x, qb0.y*kb0.y); af[3].u[1] = pk2(qb0.z*kb0.z, qb0.w*kb0.w);
    af[3].u[2] = pk2(qb1.x*kb1.x, qb1.y*kb1.y); af[3].u[3] = pk2(qb1.z*kb1.z, qb1.w*kb1.w);

    #pragma unroll
    for (int mt = 0; mt < 4; ++mt)
      #pragma unroll
      for (int nt = 0; nt < 8; ++nt)
        acc[mt][nt] = __builtin_amdgcn_mfma_f32_16x16x32_bf16(af[mt].v, bcur[nt], acc[mt][nt], 0, 0, 0);
    if (kc < 7) {
      #pragma unroll
      for (int nt = 0; nt < 8; ++nt) bcur[nt] = bnxt[nt];
    }
  }

  float w20[8], w21[8];
  #pragma unroll
  for (int nt = 0; nt < 8; ++nt) {
    int n = nwv * 128 + nt * 16 + l15;
    w20[nt] = w2[n * 2];
    w21[nt] = w2[n * 2 + 1];
  }
  #pragma unroll
  for (int mt = 0; mt < 4; ++mt) {
    #pragma unroll
    for (int reg = 0; reg < 4; ++reg) {
      int r = mwv * 64 + mt * 16 + q4 * 4 + reg;
      int lc = (r >> 5) - (r & 31) + 31;
      float o0 = 0.f, o1 = 0.f;
      #pragma unroll
      for (int nt = 0; nt < 8; ++nt) {
        int n = nwv * 128 + nt * 16 + l15;
        float T = acc[mt][nt][reg] + RB_s[lc * 260 + n];
        T = fmaxf(T, 0.f);
        o0 = fmaf(T, w20[nt], o0);
        o1 = fmaf(T, w21[nt], o1);
      }
      #pragma unroll
      for (int s = 1; s < 16; s <<= 1) {
        o0 += __shfl_xor(o0, s);
        o1 += __shfl_xor(o1, s);
      }
      if (l15 == 0) {
        atomicAdd(&racc[r * 2 + 0], o0);
        atomicAdd(&racc[r * 2 + 1], o1);
      }
    }
  }
  __syncthreads();
  {
    int r = t >> 1, oo = t & 1;
    out[((size_t)(i0 + (r >> 5)) * LSEQ + (j0 + (r & 31))) * 2 + oo] = racc[t] + b2[oo];
  }
}

// ---------------------------------------------------------------------------
extern "C" void kernel_launch(void* const* d_in, const int* in_sizes, int n_in,
                              void* d_out, int out_size, void* d_ws, size_t ws_size,
                              hipStream_t stream) {
  const int*   seq      = (const int*)  d_in[0];
  const float* tok_emb  = (const float*)d_in[1];
  const float* rp_emb   = (const float*)d_in[2];
  const float* wq       = (const float*)d_in[3];
  const float* wk       = (const float*)d_in[4];
  const float* wv       = (const float*)d_in[5];
  const float* wo       = (const float*)d_in[6];
  const float* ln1_s    = (const float*)d_in[7];
  const float* ln1_b    = (const float*)d_in[8];
  const float* ln2_s    = (const float*)d_in[9];
  const float* ln2_b    = (const float*)d_in[10];
  const float* ffn_w1   = (const float*)d_in[11];
  const float* ffn_b1   = (const float*)d_in[12];
  const float* ffn_w2   = (const float*)d_in[13];
  const float* ffn_b2   = (const float*)d_in[14];
  const float* lnf_s    = (const float*)d_in[15];
  const float* lnf_b    = (const float*)d_in[16];
  const float* pair_q_w = (const float*)d_in[17];
  const float* pair_q_b = (const float*)d_in[18];
  const float* pair_k_w = (const float*)d_in[19];
  const float* pair_k_b = (const float*)d_in[20];
  const float* pair_rp  = (const float*)d_in[21];
  const float* cls_w1   = (const float*)d_in[22];
  const float* cls_b1   = (const float*)d_in[23];
  const float* cls_w2   = (const float*)d_in[24];
  const float* cls_b2   = (const float*)d_in[25];
  float* out = (float*)d_out;

  char* ws = (char*)d_ws;
  float* xb0 = (float*)(ws + 0);
  float* xb1 = (float*)(ws + 786432);
  float* qb[2] = { (float*)(ws + 1572864), (float*)(ws + 3932160) };
  float* kb[2] = { (float*)(ws + 2359296), (float*)(ws + 4718592) };
  float* vb[2] = { (float*)(ws + 3145728), (float*)(ws + 5505024) };
  float* o   = (float*)(ws + 6291456);
  float* f1  = (float*)(ws + 7077888);
  float* pq  = (float*)(ws + 10223616);
  float* pk  = (float*)(ws + 11010048);
  float* RB  = (float*)(ws + 11796480);
  unsigned short* W1p = (unsigned short*)(ws + 13369344);
  float* abias = (float*)(ws + 13500416);

  (void)in_sizes; (void)n_in; (void)out_size; (void)ws_size;

  hipFuncSetAttribute(reinterpret_cast<const void*>(k_pair),
                      hipFuncAttributeMaxDynamicSharedMemorySize, PAIR_SMEM);
  hipFuncSetAttribute(reinterpret_cast<const void*>(k_attn2),
                      hipFuncAttributeMaxDynamicSharedMemorySize, ATTN_SMEM);

  k_prep<<<502, 256, 0, stream>>>(seq, tok_emb, rp_emb, wq, wk, wv,
                                  ln1_s, ln1_b, pair_rp, cls_w1, cls_b1,
                                  xb0, qb[0], kb[0], vb[0], RB, W1p, abias);

  for (int l = 0; l < NLAYER; ++l) {
    int pi = l & 1, po = pi ^ 1;
    float* xin  = (l & 1) ? xb1 : xb0;
    float* xout = (l & 1) ? xb0 : xb1;

    // attention
    k_attn2<<<dim3(48, 8), 256, ATTN_SMEM, stream>>>(qb[pi], kb[pi], vb[pi], abias, o);

    // wo: xout = xin + o @ Wo
    {
      GA a{};
      a.A = o; a.B0 = wo + (size_t)l * DM * DM; a.C0 = xout; a.res = xin;
      a.K = 256; a.Nper = 256; a.ldA = 256; a.ntile = 2;
      k_gemm<0,0,1,0><<<dim3(2, 12), 256, 0, stream>>>(a);
    }
    // ffn1: f1 = gelu(LN2(xout) @ fw1 + fb1)
    {
      GA a{};
      a.A = xout; a.B0 = ffn_w1 + (size_t)l * DM * DFF;
      a.bias0 = ffn_b1 + (size_t)l * DFF; a.C0 = f1;
      a.lns = ln2_s + l * DM; a.lnb = ln2_b + l * DM;
      a.K = 256; a.Nper = 1024; a.ldA = 256; a.ntile = 8;
      k_gemm<1,1,0,0><<<dim3(8, 12), 256, 0, stream>>>(a);
    }
    // ffn2 (split-K=2, atomicAdd): xout += f1 @ fw2 + fb2
    {
      GA a{};
      a.A = f1; a.B0 = ffn_w2 + (size_t)l * DFF * DM;
      a.bias0 = ffn_b2 + (size_t)l * DM; a.C0 = xout;
      a.K = 512; a.Nper = 256; a.ldA = 1024; a.ntile = 2;
      k_gemm<0,0,0,1><<<dim3(2, 12, 2), 256, 0, stream>>>(a);
    }
    if (l < NLAYER - 1) {
      // qkv for next layer
      GA a{};
      a.A = xout;
      a.B0 = wq + (size_t)(l + 1) * DM * DM;
      a.B1 = wk + (size_t)(l + 1) * DM * DM;
      a.B2 = wv + (size_t)(l + 1) * DM * DM;
      a.C0 = qb[po]; a.C1 = kb[po]; a.C2 = vb[po];
      a.lns = ln1_s + (l + 1) * DM; a.lnb = ln1_b + (l + 1) * DM;
      a.K = 256; a.Nper = 256; a.ldA = 256; a.ntile = 2;
      k_gemm<1,0,0,0><<<dim3(6, 12), 256, 0, stream>>>(a);
    } else {
      // pair projection
      GA a{};
      a.A = xout;
      a.B0 = pair_q_w; a.B1 = pair_k_w;
      a.bias0 = pair_q_b; a.bias1 = pair_k_b;
      a.C0 = pq; a.C1 = pk;
      a.lns = lnf_s; a.lnb = lnf_b;
      a.K = 256; a.Nper = 256; a.ldA = 256; a.ntile = 2;
      k_gemm<1,0,0,0><<<dim3(4, 12), 256, 0, stream>>>(a);
    }
  }

  k_pair<<<dim3(24, 192), 256, PAIR_SMEM, stream>>>(pq, pk, W1p, RB, cls_w2, cls_b2, out);
}

// Round 8
// 1360.899 us; speedup vs baseline: 2.4171x; 1.2670x over previous
//
#include <hip/hip_runtime.h>
#include <hip/hip_bf16.h>
#include <stdint.h>

// ---------------------------------------------------------------------------
#define LSEQ 768
#define DM   256
#define NH   8
#define DK   32
#define DFF  1024
#define NLAYER 8
#define NDD  1535
// ---------------------------------------------------------------------------

typedef __attribute__((ext_vector_type(8))) short  bf16x8;
typedef __attribute__((ext_vector_type(4))) float  f32x4;

__device__ __forceinline__ unsigned short f2bf(float f) {
  unsigned u = __float_as_uint(f);
  u += 0x7fffu + ((u >> 16) & 1u);       // RNE
  return (unsigned short)(u >> 16);
}
__device__ __forceinline__ unsigned pk2(float a, float b) {
  __hip_bfloat162 h = __float22bfloat162_rn(make_float2(a, b));
  union { __hip_bfloat162 h; unsigned u; } c; c.h = h;
  return c.u;
}
__device__ __forceinline__ int bucket_of(int dd) {
  int rel = dd - 767;
  int ret = rel < 0 ? 32 : 0;
  int arp = rel < 0 ? -rel : rel;
  if (arp < 16) return ret + arp;
  const float lr = 2.772588722239781f;   // float(np.log(16))
  float val = logf((float)arp * 0.0625f) / lr * 16.0f;
  int vi = 16 + (int)val;
  return ret + (vi < 31 ? vi : 31);
}

// ---------------------------------------------------------------------------
// Legacy 64x64 GEMM tile (k_prep only; plain caching, gather variants).
// LDS from smc: As 2x32x68 @0, Bs @17408, stat @34816, red @35328 -> 37376.
template <int LN, int GR>
__device__ void gemm_tile(const float* gsrc, const int* seqIdx,
                          const float* B, const float* bias, float* C,
                          const float* lns, const float* lnb,
                          int M, int K, int N, int m0, int n0, char* smc) {
  float (*As)[32][68] = (float (*)[32][68])smc;
  float (*Bs)[32][68] = (float (*)[32][68])(smc + 17408);
  float (*stat)[2]    = (float (*)[2])(smc + 34816);
  float (*red)[8]     = (float (*)[8])(smc + 35328);

  int t = threadIdx.x;
  int arow = t >> 2, akq = (t & 3) * 8;
  int mg = m0 + arow;
  int mgc = mg < M ? mg : M - 1;
  const float* Ar = (GR == 1) ? (gsrc + (size_t)seqIdx[mgc] * K)
                              : (gsrc + (size_t)bucket_of(mgc) * K);
  float mean = 0.f, rstd = 0.f;
  if (LN) {
    int lq = t & 3;
    float s = 0.f, s2 = 0.f;
    const float* p = Ar + lq * 64;
    #pragma unroll
    for (int c = 0; c < 64; c += 4) {
      float4 v = *(const float4*)(p + c);
      s  += v.x + v.y + v.z + v.w;
      s2 += v.x * v.x + v.y * v.y + v.z * v.z + v.w * v.w;
    }
    red[arow][lq] = s; red[arow][lq + 4] = s2;
    __syncthreads();
    if (lq == 0) {
      float sm = red[arow][0] + red[arow][1] + red[arow][2] + red[arow][3];
      float sq = red[arow][4] + red[arow][5] + red[arow][6] + red[arow][7];
      float m = sm * (1.f / 256.f);
      float v = sq * (1.f / 256.f) - m * m;
      stat[arow][0] = m;
      stat[arow][1] = rsqrtf(v + 1e-5f);
    }
    __syncthreads();
    mean = stat[arow][0]; rstd = stat[arow][1];
  }

  int bkr = t >> 3, bn8 = (t & 7) * 8;
  int ty = t >> 4, tx = t & 15;
  float acc[4][4] = {};
  int nk = K >> 5;

  for (int kt = 0; kt < nk; ++kt) {
    int k0 = kt << 5;
    float4 a0 = *(const float4*)(Ar + k0 + akq);
    float4 a1 = *(const float4*)(Ar + k0 + akq + 4);
    if (LN) {
      float4 ls0 = *(const float4*)(lns + k0 + akq), ls1 = *(const float4*)(lns + k0 + akq + 4);
      float4 lb0 = *(const float4*)(lnb + k0 + akq), lb1 = *(const float4*)(lnb + k0 + akq + 4);
      a0.x=(a0.x-mean)*rstd*ls0.x+lb0.x; a0.y=(a0.y-mean)*rstd*ls0.y+lb0.y;
      a0.z=(a0.z-mean)*rstd*ls0.z+lb0.z; a0.w=(a0.w-mean)*rstd*ls0.w+lb0.w;
      a1.x=(a1.x-mean)*rstd*ls1.x+lb1.x; a1.y=(a1.y-mean)*rstd*ls1.y+lb1.y;
      a1.z=(a1.z-mean)*rstd*ls1.z+lb1.z; a1.w=(a1.w-mean)*rstd*ls1.w+lb1.w;
    }
    int cur = kt & 1;
    As[cur][akq+0][arow]=a0.x; As[cur][akq+1][arow]=a0.y; As[cur][akq+2][arow]=a0.z; As[cur][akq+3][arow]=a0.w;
    As[cur][akq+4][arow]=a1.x; As[cur][akq+5][arow]=a1.y; As[cur][akq+6][arow]=a1.z; As[cur][akq+7][arow]=a1.w;
    *(float4*)&Bs[cur][bkr][bn8] = *(const float4*)(B + (size_t)(k0 + bkr) * N + n0 + bn8);
    *(float4*)&Bs[cur][bkr][bn8+4] = *(const float4*)(B + (size_t)(k0 + bkr) * N + n0 + bn8 + 4);
    __syncthreads();
    #pragma unroll 8
    for (int kk = 0; kk < 32; ++kk) {
      float4 a = *(float4*)&As[cur][kk][ty * 4];
      float4 b = *(float4*)&Bs[cur][kk][tx * 4];
      acc[0][0]=fmaf(a.x,b.x,acc[0][0]); acc[0][1]=fmaf(a.x,b.y,acc[0][1]);
      acc[0][2]=fmaf(a.x,b.z,acc[0][2]); acc[0][3]=fmaf(a.x,b.w,acc[0][3]);
      acc[1][0]=fmaf(a.y,b.x,acc[1][0]); acc[1][1]=fmaf(a.y,b.y,acc[1][1]);
      acc[1][2]=fmaf(a.y,b.z,acc[1][2]); acc[1][3]=fmaf(a.y,b.w,acc[1][3]);
      acc[2][0]=fmaf(a.z,b.x,acc[2][0]); acc[2][1]=fmaf(a.z,b.y,acc[2][1]);
      acc[2][2]=fmaf(a.z,b.z,acc[2][2]); acc[2][3]=fmaf(a.z,b.w,acc[2][3]);
      acc[3][0]=fmaf(a.w,b.x,acc[3][0]); acc[3][1]=fmaf(a.w,b.y,acc[3][1]);
      acc[3][2]=fmaf(a.w,b.z,acc[3][2]); acc[3][3]=fmaf(a.w,b.w,acc[3][3]);
    }
    __syncthreads();
  }

  #pragma unroll
  for (int u = 0; u < 4; ++u) {
    int m = m0 + ty * 4 + u;
    if (m < M) {
      int n = n0 + tx * 4;
      float4 val = make_float4(acc[u][0], acc[u][1], acc[u][2], acc[u][3]);
      if (bias) {
        float4 bv = *(const float4*)(bias + n);
        val.x += bv.x; val.y += bv.y; val.z += bv.z; val.w += bv.w;
      }
      *(float4*)(C + (size_t)m * N + n) = val;
    }
  }
}

// ---------------------------------------------------------------------------
// Prep: RB gemm + qkv layer0 + embed + abias + W1p pack. One dispatch.
__global__ __launch_bounds__(256, 2) void k_prep(
    const int* __restrict__ seq, const float* __restrict__ tok_emb,
    const float* __restrict__ rp_emb,
    const float* __restrict__ wq0, const float* __restrict__ wk0,
    const float* __restrict__ wv0,
    const float* __restrict__ ln1s0, const float* __restrict__ ln1b0,
    const float* __restrict__ pair_rp, const float* __restrict__ cls_w1,
    const float* __restrict__ cls_b1,
    float* x0, float* q0, float* k0, float* v0, float* RB,
    unsigned short* W1p, float* abias) {
  __shared__ __align__(16) char sm[37376];
  int b = blockIdx.x, t = threadIdx.x;
  if (b < 96) {
    int m0 = (b % 24) * 64, n0 = (b / 24) * 64;
    gemm_tile<0,2>(pair_rp, nullptr, cls_w1, cls_b1, RB,
                   nullptr, nullptr, NDD, 256, 256, m0, n0, sm);
  } else if (b < 240) {
    int u = b - 96;
    int n0g = (u % 12) * 64, m0 = (u / 12) * 64;
    int bi = n0g >> 8, n0 = n0g & 255;
    const float* B = bi == 0 ? wq0 : (bi == 1 ? wk0 : wv0);
    float* C = bi == 0 ? q0 : (bi == 1 ? k0 : v0);
    gemm_tile<1,1>(tok_emb, seq, B, nullptr, C,
                   ln1s0, ln1b0, LSEQ, 256, 256, m0, n0, sm);
  } else if (b < 432) {
    int row = (b - 240) * 4 + (t >> 6), c = (t & 63) * 4;
    *(float4*)(x0 + (size_t)row * DM + c) =
        *(const float4*)(tok_emb + (size_t)seq[row] * DM + c);
  } else if (b < 438) {
    int dd = (b - 432) * 256 + t;
    if (dd < NDD) {
      int bk = bucket_of(dd);
      #pragma unroll
      for (int h = 0; h < NH; ++h) abias[dd * 8 + h] = rp_emb[bk * 8 + h];
    }
  } else {
    int base = (b - 438) * 1024 + t * 4;
    #pragma unroll
    for (int uu = 0; uu < 4; ++uu) {
      int id = base + uu;
      int e = id & 7, lane = (id >> 3) & 63, g = (id >> 9) & 15, kc = id >> 13;
      int kg = kc * 32 + (lane >> 4) * 8 + e;
      int n  = g * 16 + (lane & 15);
      W1p[id] = f2bf(cls_w1[(size_t)kg * 256 + n]);
    }
  }
}

// ---------------------------------------------------------------------------
// Attention (validated round 7): 16 q-rows x 1 head per block.
#define ATTN_SMEM 72960

__global__ __launch_bounds__(256, 2) void k_attn2(
    const float* __restrict__ q, const float* __restrict__ k,
    const float* __restrict__ v, const float* __restrict__ abias,
    float* __restrict__ o) {
  extern __shared__ char sm[];
  float* S  = (float*)sm;
  float* KV = (float*)(sm + 49664);
  float* QS = (float*)(sm + 66560);
  float* BS = (float*)(sm + 68672);
  float (*red)[16] = (float (*)[16])(sm + 71808);
  float* mrow = (float*)(sm + 72832);
  float* linv = (float*)(sm + 72896);

  int i0 = blockIdx.x * 16, h = blockIdx.y, hc = h * DK;
  int t = threadIdx.x;

  for (int u = t; u < 783; u += 256)
    BS[u] = abias[(size_t)(i0 + u) * 8 + h];
  {
    int r = t >> 4, c = t & 15;
    const float inv = 0.17677669529663687f;   // 1/sqrt(32)
    QS[r * 33 + c]      = q[(size_t)(i0 + r) * DM + hc + c] * inv;
    QS[r * 33 + c + 16] = q[(size_t)(i0 + r) * DM + hc + c + 16] * inv;
  }

  int kx = t & 31, ry = t >> 5;
  int key = t >> 1, half = t & 1;

  for (int cc = 0; cc < 6; ++cc) {
    const float* kp = k + (size_t)(cc * 128 + key) * DM + hc + half * 16;
    float4 L0 = *(const float4*)(kp);
    float4 L1 = *(const float4*)(kp + 4);
    float4 L2 = *(const float4*)(kp + 8);
    float4 L3 = *(const float4*)(kp + 12);
    __syncthreads();
    int cb = half * 16;
    KV[(cb+ 0)*132+key]=L0.x; KV[(cb+ 1)*132+key]=L0.y; KV[(cb+ 2)*132+key]=L0.z; KV[(cb+ 3)*132+key]=L0.w;
    KV[(cb+ 4)*132+key]=L1.x; KV[(cb+ 5)*132+key]=L1.y; KV[(cb+ 6)*132+key]=L1.z; KV[(cb+ 7)*132+key]=L1.w;
    KV[(cb+ 8)*132+key]=L2.x; KV[(cb+ 9)*132+key]=L2.y; KV[(cb+10)*132+key]=L2.z; KV[(cb+11)*132+key]=L2.w;
    KV[(cb+12)*132+key]=L3.x; KV[(cb+13)*132+key]=L3.y; KV[(cb+14)*132+key]=L3.z; KV[(cb+15)*132+key]=L3.w;
    __syncthreads();

    float s0x=0,s0y=0,s0z=0,s0w=0, s1x=0,s1y=0,s1z=0,s1w=0;
    #pragma unroll
    for (int kk = 0; kk < 32; ++kk) {
      float q0 = QS[(ry*2    )*33 + kk];
      float q1 = QS[(ry*2 + 1)*33 + kk];
      float4 kv4 = *(const float4*)&KV[kk*132 + kx*4];
      s0x = fmaf(q0, kv4.x, s0x); s0y = fmaf(q0, kv4.y, s0y);
      s0z = fmaf(q0, kv4.z, s0z); s0w = fmaf(q0, kv4.w, s0w);
      s1x = fmaf(q1, kv4.x, s1x); s1y = fmaf(q1, kv4.y, s1y);
      s1z = fmaf(q1, kv4.z, s1z); s1w = fmaf(q1, kv4.w, s1w);
    }
    int jb = cc * 128 + kx * 4;
    int r0 = ry * 2, r1 = r0 + 1;
    S[r0*776 + jb+0] = s0x + BS[r0 + 767 - (jb+0)];
    S[r0*776 + jb+1] = s0y + BS[r0 + 767 - (jb+1)];
    S[r0*776 + jb+2] = s0z + BS[r0 + 767 - (jb+2)];
    S[r0*776 + jb+3] = s0w + BS[r0 + 767 - (jb+3)];
    S[r1*776 + jb+0] = s1x + BS[r1 + 767 - (jb+0)];
    S[r1*776 + jb+1] = s1y + BS[r1 + 767 - (jb+1)];
    S[r1*776 + jb+2] = s1z + BS[r1 + 767 - (jb+2)];
    S[r1*776 + jb+3] = s1w + BS[r1 + 767 - (jb+3)];
  }
  __syncthreads();

  {
    int ti = t >> 4, tj = t & 15;
    float mx = -1e30f;
    for (int jc = 0; jc < 48; ++jc)
      mx = fmaxf(mx, S[ti*776 + jc*16 + tj]);
    red[ti][tj] = mx;
    __syncthreads();
    if (tj == 0) {
      float m2 = red[ti][0];
      #pragma unroll
      for (int u = 1; u < 16; ++u) m2 = fmaxf(m2, red[ti][u]);
      mrow[ti] = m2;
    }
    __syncthreads();
    float m2 = mrow[ti];
    float sum = 0.f;
    for (int jc = 0; jc < 48; ++jc) {
      int j = jc*16 + tj;
      float e = __expf(S[ti*776 + j] - m2);
      S[ti*776 + j] = e;
      sum += e;
    }
    red[ti][tj] = sum;
    __syncthreads();
    if (tj == 0) {
      float s2 = 0.f;
      #pragma unroll
      for (int u = 0; u < 16; ++u) s2 += red[ti][u];
      linv[ti] = 1.f / s2;
    }
  }

  int cp = t & 15, jg = t >> 4;
  int c0 = cp * 2, c1 = c0 + 1;
  float oc0[16] = {}, oc1[16] = {};
  for (int cc = 0; cc < 6; ++cc) {
    const float* vp = v + (size_t)(cc * 128 + key) * DM + hc + half * 16;
    float4 L0 = *(const float4*)(vp);
    float4 L1 = *(const float4*)(vp + 4);
    float4 L2 = *(const float4*)(vp + 8);
    float4 L3 = *(const float4*)(vp + 12);
    __syncthreads();
    int cb = half * 16;
    KV[(cb+ 0)*132+key]=L0.x; KV[(cb+ 1)*132+key]=L0.y; KV[(cb+ 2)*132+key]=L0.z; KV[(cb+ 3)*132+key]=L0.w;
    KV[(cb+ 4)*132+key]=L1.x; KV[(cb+ 5)*132+key]=L1.y; KV[(cb+ 6)*132+key]=L1.z; KV[(cb+ 7)*132+key]=L1.w;
    KV[(cb+ 8)*132+key]=L2.x; KV[(cb+ 9)*132+key]=L2.y; KV[(cb+10)*132+key]=L2.z; KV[(cb+11)*132+key]=L2.w;
    KV[(cb+12)*132+key]=L3.x; KV[(cb+13)*132+key]=L3.y; KV[(cb+14)*132+key]=L3.z; KV[(cb+15)*132+key]=L3.w;
    __syncthreads();

    #pragma unroll
    for (int jj2 = 0; jj2 < 2; ++jj2) {
      int jb = jg * 8 + jj2 * 4;
      float4 vA = *(const float4*)&KV[c0*132 + jb];
      float4 vB = *(const float4*)&KV[c1*132 + jb];
      #pragma unroll
      for (int r = 0; r < 16; ++r) {
        float4 sv = *(const float4*)&S[r*776 + cc*128 + jb];
        oc0[r] += sv.x*vA.x + sv.y*vA.y + sv.z*vA.z + sv.w*vA.w;
        oc1[r] += sv.x*vB.x + sv.y*vB.y + sv.z*vB.z + sv.w*vB.w;
      }
    }
  }

  #pragma unroll
  for (int h2 = 0; h2 < 2; ++h2) {
    __syncthreads();
    #pragma unroll
    for (int r = 0; r < 8; ++r) {
      KV[(jg*8 + r)*32 + c0] = oc0[h2*8 + r];
      KV[(jg*8 + r)*32 + c1] = oc1[h2*8 + r];
    }
    __syncthreads();
    int r = t >> 5, c = t & 31;
    float s = 0.f;
    #pragma unroll
    for (int jgg = 0; jgg < 16; ++jgg) s += KV[(jgg*8 + r)*32 + c];
    o[(size_t)(i0 + h2*8 + r) * DM + hc + c] = s * linv[h2*8 + r];
  }
}

// ---------------------------------------------------------------------------
// Fused layer tail: wo+res -> LN2 -> ffn1(gelu) -> ffn2+res -> LN1next -> qkv
// (or pair projection on last layer). Row-local: block owns 4 rows; all
// intermediates in LDS; weights stream coalesced from L2 (each element once).
// 192 blocks x 256 threads; thread t owns output column t.
struct TA {
  const float* o; const float* xin;
  const float* wo; const float* ln2s; const float* ln2b;
  const float* fw1; const float* fb1; const float* fw2; const float* fb2;
  const float* wn0; const float* wn1; const float* wn2;
  const float* lns; const float* lnb; const float* nb0; const float* nb1;
  float *qo, *ko, *vo, *xo;
};

__device__ __forceinline__ void ln4(float (*X)[260], float (*H)[260],
                                    const float* s, const float* b,
                                    float (*red)[64], float (*red2)[64],
                                    float* st, int t) {
  int r = t >> 6, g = t & 63;
  float s1 = 0.f, s2 = 0.f;
  #pragma unroll
  for (int u = 0; u < 4; ++u) {
    float x = X[r][g * 4 + u];
    s1 += x; s2 += x * x;
  }
  red[r][g] = s1; red2[r][g] = s2;
  __syncthreads();
  if (g == 0) {
    float a1 = 0.f, a2 = 0.f;
    #pragma unroll
    for (int u = 0; u < 64; ++u) { a1 += red[r][u]; a2 += red2[r][u]; }
    float m = a1 * (1.f / 256.f);
    float v = a2 * (1.f / 256.f) - m * m;
    st[r] = m; st[4 + r] = rsqrtf(v + 1e-5f);
  }
  __syncthreads();
  float m = st[r], rs = st[4 + r];
  #pragma unroll
  for (int u = 0; u < 4; ++u) {
    int c = g * 4 + u;
    H[r][c] = (X[r][c] - m) * rs * s[c] + b[c];
  }
  __syncthreads();
}

template <int LAST>
__global__ __launch_bounds__(256, 2) void k_tail(TA a) {
  __shared__ float OSs[4][260];
  __shared__ float XO[4][260];
  __shared__ float H[4][260];
  __shared__ float F1[4][1024];
  __shared__ float red[4][64], red2[4][64];
  __shared__ float st[8];
  int t = threadIdx.x;
  int i0 = blockIdx.x * 4;

  // stage o rows (4x256)
  {
    int r = t >> 6, c = (t & 63) * 4;
    *(float4*)&OSs[r][c] = *(const float4*)(a.o + (size_t)(i0 + r) * DM + c);
  }
  __syncthreads();

  // ---- wo + residual -> XO ----
  {
    float a0 = 0.f, a1 = 0.f, a2 = 0.f, a3 = 0.f;
    #pragma unroll 4
    for (int k4 = 0; k4 < 64; ++k4) {
      int kk = k4 * 4;
      float4 o0 = *(float4*)&OSs[0][kk];
      float4 o1 = *(float4*)&OSs[1][kk];
      float4 o2 = *(float4*)&OSs[2][kk];
      float4 o3 = *(float4*)&OSs[3][kk];
      float b0 = a.wo[(size_t)(kk + 0) * DM + t];
      float b1 = a.wo[(size_t)(kk + 1) * DM + t];
      float b2 = a.wo[(size_t)(kk + 2) * DM + t];
      float b3 = a.wo[(size_t)(kk + 3) * DM + t];
      a0 += o0.x*b0 + o0.y*b1 + o0.z*b2 + o0.w*b3;
      a1 += o1.x*b0 + o1.y*b1 + o1.z*b2 + o1.w*b3;
      a2 += o2.x*b0 + o2.y*b1 + o2.z*b2 + o2.w*b3;
      a3 += o3.x*b0 + o3.y*b1 + o3.z*b2 + o3.w*b3;
    }
    XO[0][t] = a.xin[(size_t)(i0 + 0) * DM + t] + a0;
    XO[1][t] = a.xin[(size_t)(i0 + 1) * DM + t] + a1;
    XO[2][t] = a.xin[(size_t)(i0 + 2) * DM + t] + a2;
    XO[3][t] = a.xin[(size_t)(i0 + 3) * DM + t] + a3;
  }
  __syncthreads();

  // ---- LN2 -> H ----
  ln4(XO, H, a.ln2s, a.ln2b, red, red2, st, t);

  // ---- ffn1 -> F1 (gelu) ----
  {
    float ac[4][4] = {};
    #pragma unroll 4
    for (int kk = 0; kk < 256; ++kk) {
      float h0 = H[0][kk], h1 = H[1][kk], h2 = H[2][kk], h3 = H[3][kk];
      float b0 = a.fw1[(size_t)kk * DFF + t];
      float b1 = a.fw1[(size_t)kk * DFF + 256 + t];
      float b2 = a.fw1[(size_t)kk * DFF + 512 + t];
      float b3 = a.fw1[(size_t)kk * DFF + 768 + t];
      ac[0][0] += h0*b0; ac[0][1] += h0*b1; ac[0][2] += h0*b2; ac[0][3] += h0*b3;
      ac[1][0] += h1*b0; ac[1][1] += h1*b1; ac[1][2] += h1*b2; ac[1][3] += h1*b3;
      ac[2][0] += h2*b0; ac[2][1] += h2*b1; ac[2][2] += h2*b2; ac[2][3] += h2*b3;
      ac[3][0] += h3*b0; ac[3][1] += h3*b1; ac[3][2] += h3*b2; ac[3][3] += h3*b3;
    }
    #pragma unroll
    for (int nq = 0; nq < 4; ++nq) {
      float bb = a.fb1[nq * 256 + t];
      #pragma unroll
      for (int r = 0; r < 4; ++r) {
        float v = ac[r][nq] + bb;
        v = 0.5f * v * (1.f + erff(v * 0.70710678118654752f));
        F1[r][nq * 256 + t] = v;
      }
    }
  }
  __syncthreads();

  // ---- ffn2 + residual -> XO, store xout ----
  {
    float a0 = 0.f, a1 = 0.f, a2 = 0.f, a3 = 0.f;
    #pragma unroll 4
    for (int k4 = 0; k4 < 256; ++k4) {
      int kk = k4 * 4;
      float4 f0 = *(float4*)&F1[0][kk];
      float4 f1v = *(float4*)&F1[1][kk];
      float4 f2 = *(float4*)&F1[2][kk];
      float4 f3 = *(float4*)&F1[3][kk];
      float b0 = a.fw2[(size_t)(kk + 0) * DM + t];
      float b1 = a.fw2[(size_t)(kk + 1) * DM + t];
      float b2 = a.fw2[(size_t)(kk + 2) * DM + t];
      float b3 = a.fw2[(size_t)(kk + 3) * DM + t];
      a0 += f0.x*b0 + f0.y*b1 + f0.z*b2 + f0.w*b3;
      a1 += f1v.x*b0 + f1v.y*b1 + f1v.z*b2 + f1v.w*b3;
      a2 += f2.x*b0 + f2.y*b1 + f2.z*b2 + f2.w*b3;
      a3 += f3.x*b0 + f3.y*b1 + f3.z*b2 + f3.w*b3;
    }
    float bb = a.fb2[t];
    float x0 = XO[0][t] + a0 + bb;
    float x1 = XO[1][t] + a1 + bb;
    float x2 = XO[2][t] + a2 + bb;
    float x3 = XO[3][t] + a3 + bb;
    XO[0][t] = x0; XO[1][t] = x1; XO[2][t] = x2; XO[3][t] = x3;
    a.xo[(size_t)(i0 + 0) * DM + t] = x0;
    a.xo[(size_t)(i0 + 1) * DM + t] = x1;
    a.xo[(size_t)(i0 + 2) * DM + t] = x2;
    a.xo[(size_t)(i0 + 3) * DM + t] = x3;
  }
  __syncthreads();

  // ---- LN1-next (or LNf) -> H ----
  ln4(XO, H, a.lns, a.lnb, red, red2, st, t);

  // ---- qkv next / pair projection ----
  if (!LAST) {
    float aq0=0,aq1=0,aq2=0,aq3=0, ak0=0,ak1=0,ak2=0,ak3=0, av0=0,av1=0,av2=0,av3=0;
    #pragma unroll 2
    for (int kk = 0; kk < 256; ++kk) {
      float h0 = H[0][kk], h1 = H[1][kk], h2 = H[2][kk], h3 = H[3][kk];
      float bq = a.wn0[(size_t)kk * DM + t];
      float bk = a.wn1[(size_t)kk * DM + t];
      float bv = a.wn2[(size_t)kk * DM + t];
      aq0 += h0*bq; aq1 += h1*bq; aq2 += h2*bq; aq3 += h3*bq;
      ak0 += h0*bk; ak1 += h1*bk; ak2 += h2*bk; ak3 += h3*bk;
      av0 += h0*bv; av1 += h1*bv; av2 += h2*bv; av3 += h3*bv;
    }
    a.qo[(size_t)(i0+0)*DM + t] = aq0; a.qo[(size_t)(i0+1)*DM + t] = aq1;
    a.qo[(size_t)(i0+2)*DM + t] = aq2; a.qo[(size_t)(i0+3)*DM + t] = aq3;
    a.ko[(size_t)(i0+0)*DM + t] = ak0; a.ko[(size_t)(i0+1)*DM + t] = ak1;
    a.ko[(size_t)(i0+2)*DM + t] = ak2; a.ko[(size_t)(i0+3)*DM + t] = ak3;
    a.vo[(size_t)(i0+0)*DM + t] = av0; a.vo[(size_t)(i0+1)*DM + t] = av1;
    a.vo[(size_t)(i0+2)*DM + t] = av2; a.vo[(size_t)(i0+3)*DM + t] = av3;
  } else {
    float aq0=0,aq1=0,aq2=0,aq3=0, ak0=0,ak1=0,ak2=0,ak3=0;
    #pragma unroll 2
    for (int kk = 0; kk < 256; ++kk) {
      float h0 = H[0][kk], h1 = H[1][kk], h2 = H[2][kk], h3 = H[3][kk];
      float bq = a.wn0[(size_t)kk * DM + t];
      float bk = a.wn1[(size_t)kk * DM + t];
      aq0 += h0*bq; aq1 += h1*bq; aq2 += h2*bq; aq3 += h3*bq;
      ak0 += h0*bk; ak1 += h1*bk; ak2 += h2*bk; ak3 += h3*bk;
    }
    float bq0 = a.nb0[t], bk0 = a.nb1[t];
    a.qo[(size_t)(i0+0)*DM + t] = aq0 + bq0; a.qo[(size_t)(i0+1)*DM + t] = aq1 + bq0;
    a.qo[(size_t)(i0+2)*DM + t] = aq2 + bq0; a.qo[(size_t)(i0+3)*DM + t] = aq3 + bq0;
    a.ko[(size_t)(i0+0)*DM + t] = ak0 + bk0; a.ko[(size_t)(i0+1)*DM + t] = ak1 + bk0;
    a.ko[(size_t)(i0+2)*DM + t] = ak2 + bk0; a.ko[(size_t)(i0+3)*DM + t] = ak3 + bk0;
  }
}

// ---------------------------------------------------------------------------
// Fused pair head (validated): LDS-staged q/k, W1p reg-prefetch, packed cvt.
#define PAIR_SMEM 74864

__global__ __launch_bounds__(256, 2) void k_pair(
    const float* __restrict__ pq, const float* __restrict__ pk,
    const unsigned short* __restrict__ W1p, const float* __restrict__ RB,
    const float* __restrict__ w2, const float* __restrict__ b2,
    float* __restrict__ out) {
  extern __shared__ char smem[];
  float* qs   = (float*)smem;
  float* ks   = (float*)(smem + 4160);
  float* RB_s = (float*)(smem + 37440);
  float* racc = (float*)(smem + 73840);

  int t = threadIdx.x;
  int j0 = blockIdx.x * 32;
  int i0 = blockIdx.y * 4;
  int w = t >> 6, l = t & 63;
  int q4 = l >> 4, l15 = l & 15;
  int mwv = w & 1, nwv = w >> 1;

  {
    int row = t >> 6, c4 = (t & 63) * 4;
    *(float4*)(qs + row * 260 + c4) = *(const float4*)(pq + (size_t)(i0 + row) * DM + c4);
    #pragma unroll
    for (int r8 = 0; r8 < 8; ++r8) {
      int idx = t + r8 * 256;
      int kr = idx >> 6, kc4 = (idx & 63) * 4;
      *(float4*)(ks + kr * 260 + kc4) = *(const float4*)(pk + (size_t)(j0 + kr) * DM + kc4);
    }
    int ddmin = i0 - j0 + 736;
    for (int idx = t; idx < 35 * 64; idx += 256) {
      int lc = idx >> 6, c4b = (idx & 63) * 4;
      *(float4*)(RB_s + lc * 260 + c4b) =
          *(const float4*)(RB + (size_t)(ddmin + lc) * 256 + c4b);
    }
    racc[t] = 0.f;
  }
  __syncthreads();

  const unsigned short* Bp = W1p + (size_t)(nwv * 8) * 512 + (size_t)l * 8;
  const float* q0p = qs + (mwv * 2) * 260;
  const float* q1p = qs + (mwv * 2 + 1) * 260;
  const float* k0p = ks + l15 * 260;
  const float* k1p = ks + (16 + l15) * 260;

  f32x4 acc[4][8];
  #pragma unroll
  for (int aa = 0; aa < 4; ++aa)
    #pragma unroll
    for (int bb = 0; bb < 8; ++bb) acc[aa][bb] = (f32x4){0.f, 0.f, 0.f, 0.f};

  bf16x8 bcur[8];
  #pragma unroll
  for (int nt = 0; nt < 8; ++nt) bcur[nt] = *(const bf16x8*)(Bp + nt * 512);

  for (int kc = 0; kc < 8; ++kc) {
    bf16x8 bnxt[8];
    if (kc < 7) {
      const unsigned short* bbn = Bp + (size_t)(kc + 1) * 8192;
      #pragma unroll
      for (int nt = 0; nt < 8; ++nt) bnxt[nt] = *(const bf16x8*)(bbn + nt * 512);
    }
    int c = kc * 32 + q4 * 8;
    float4 qa0 = *(const float4*)(q0p + c), qa1 = *(const float4*)(q0p + c + 4);
    float4 qb0 = *(const float4*)(q1p + c), qb1 = *(const float4*)(q1p + c + 4);
    float4 ka0 = *(const float4*)(k0p + c), ka1 = *(const float4*)(k0p + c + 4);
    float4 kb0 = *(const float4*)(k1p + c), kb1 = *(const float4*)(k1p + c + 4);

    union { bf16x8 v; unsigned u[4]; } af[4];
    af[0].u[0] = pk2(qa0.x*ka0.x, qa0.y*ka0.y); af[0].u[1] = pk2(qa0.z*ka0.z, qa0.w*ka0.w);
    af[0].u[2] = pk2(qa1.x*ka1.x, qa1.y*ka1.y); af[0].u[3] = pk2(qa1.z*ka1.z, qa1.w*ka1.w);
    af[1].u[0] = pk2(qa0.x*kb0.x, qa0.y*kb0.y); af[1].u[1] = pk2(qa0.z*kb0.z, qa0.w*kb0.w);
    af[1].u[2] = pk2(qa1.x*kb1.x, qa1.y*kb1.y); af[1].u[3] = pk2(qa1.z*kb1.z, qa1.w*kb1.w);
    af[2].u[0] = pk2(qb0.x*ka0.x, qb0.y*ka0.y); af[2].u[1] = pk2(qb0.z*ka0.z, qb0.w*ka0.w);
    af[2].u[2] = pk2(qb1.x*ka1.x, qb1.y*ka1.y); af[2].u[3] = pk2(qb1.z*ka1.z, qb1.w*ka1.w);
    af[3].u[0] = pk2(qb0.x*kb0.x, qb0.y*kb0.y); af[3].u[1] = pk2(qb0.z*kb0.z, qb0.w*kb0.w);
    af[3].u[2] = pk2(qb1.x*kb1.x, qb1.y*kb1.y); af[3].u[3] = pk2(qb1.z*kb1.z, qb1.w*kb1.w);

    #pragma unroll
    for (int mt = 0; mt < 4; ++mt)
      #pragma unroll
      for (int nt = 0; nt < 8; ++nt)
        acc[mt][nt] = __builtin_amdgcn_mfma_f32_16x16x32_bf16(af[mt].v, bcur[nt], acc[mt][nt], 0, 0, 0);
    if (kc < 7) {
      #pragma unroll
      for (int nt = 0; nt < 8; ++nt) bcur[nt] = bnxt[nt];
    }
  }

  float w20[8], w21[8];
  #pragma unroll
  for (int nt = 0; nt < 8; ++nt) {
    int n = nwv * 128 + nt * 16 + l15;
    w20[nt] = w2[n * 2];
    w21[nt] = w2[n * 2 + 1];
  }
  #pragma unroll
  for (int mt = 0; mt < 4; ++mt) {
    #pragma unroll
    for (int reg = 0; reg < 4; ++reg) {
      int r = mwv * 64 + mt * 16 + q4 * 4 + reg;
      int lc = (r >> 5) - (r & 31) + 31;
      float o0 = 0.f, o1 = 0.f;
      #pragma unroll
      for (int nt = 0; nt < 8; ++nt) {
        int n = nwv * 128 + nt * 16 + l15;
        float T = acc[mt][nt][reg] + RB_s[lc * 260 + n];
        T = fmaxf(T, 0.f);
        o0 = fmaf(T, w20[nt], o0);
        o1 = fmaf(T, w21[nt], o1);
      }
      #pragma unroll
      for (int s = 1; s < 16; s <<= 1) {
        o0 += __shfl_xor(o0, s);
        o1 += __shfl_xor(o1, s);
      }
      if (l15 == 0) {
        atomicAdd(&racc[r * 2 + 0], o0);
        atomicAdd(&racc[r * 2 + 1], o1);
      }
    }
  }
  __syncthreads();
  {
    int r = t >> 1, oo = t & 1;
    out[((size_t)(i0 + (r >> 5)) * LSEQ + (j0 + (r & 31))) * 2 + oo] = racc[t] + b2[oo];
  }
}

// ---------------------------------------------------------------------------
extern "C" void kernel_launch(void* const* d_in, const int* in_sizes, int n_in,
                              void* d_out, int out_size, void* d_ws, size_t ws_size,
                              hipStream_t stream) {
  const int*   seq      = (const int*)  d_in[0];
  const float* tok_emb  = (const float*)d_in[1];
  const float* rp_emb   = (const float*)d_in[2];
  const float* wq       = (const float*)d_in[3];
  const float* wk       = (const float*)d_in[4];
  const float* wv       = (const float*)d_in[5];
  const float* wo       = (const float*)d_in[6];
  const float* ln1_s    = (const float*)d_in[7];
  const float* ln1_b    = (const float*)d_in[8];
  const float* ln2_s    = (const float*)d_in[9];
  const float* ln2_b    = (const float*)d_in[10];
  const float* ffn_w1   = (const float*)d_in[11];
  const float* ffn_b1   = (const float*)d_in[12];
  const float* ffn_w2   = (const float*)d_in[13];
  const float* ffn_b2   = (const float*)d_in[14];
  const float* lnf_s    = (const float*)d_in[15];
  const float* lnf_b    = (const float*)d_in[16];
  const float* pair_q_w = (const float*)d_in[17];
  const float* pair_q_b = (const float*)d_in[18];
  const float* pair_k_w = (const float*)d_in[19];
  const float* pair_k_b = (const float*)d_in[20];
  const float* pair_rp  = (const float*)d_in[21];
  const float* cls_w1   = (const float*)d_in[22];
  const float* cls_b1   = (const float*)d_in[23];
  const float* cls_w2   = (const float*)d_in[24];
  const float* cls_b2   = (const float*)d_in[25];
  float* out = (float*)d_out;

  char* ws = (char*)d_ws;
  float* xb0 = (float*)(ws + 0);
  float* xb1 = (float*)(ws + 786432);
  float* qb[2] = { (float*)(ws + 1572864), (float*)(ws + 3932160) };
  float* kb[2] = { (float*)(ws + 2359296), (float*)(ws + 4718592) };
  float* vb[2] = { (float*)(ws + 3145728), (float*)(ws + 5505024) };
  float* o   = (float*)(ws + 6291456);
  float* pq  = (float*)(ws + 7077888);
  float* pk  = (float*)(ws + 7864320);
  float* RB  = (float*)(ws + 8650752);
  unsigned short* W1p = (unsigned short*)(ws + 10223616);
  float* abias = (float*)(ws + 10354688);

  (void)in_sizes; (void)n_in; (void)out_size; (void)ws_size;

  hipFuncSetAttribute(reinterpret_cast<const void*>(k_pair),
                      hipFuncAttributeMaxDynamicSharedMemorySize, PAIR_SMEM);
  hipFuncSetAttribute(reinterpret_cast<const void*>(k_attn2),
                      hipFuncAttributeMaxDynamicSharedMemorySize, ATTN_SMEM);

  k_prep<<<502, 256, 0, stream>>>(seq, tok_emb, rp_emb, wq, wk, wv,
                                  ln1_s, ln1_b, pair_rp, cls_w1, cls_b1,
                                  xb0, qb[0], kb[0], vb[0], RB, W1p, abias);

  for (int l = 0; l < NLAYER; ++l) {
    int pi = l & 1, po = pi ^ 1;
    float* xin  = (l & 1) ? xb1 : xb0;
    float* xout = (l & 1) ? xb0 : xb1;

    k_attn2<<<dim3(48, 8), 256, ATTN_SMEM, stream>>>(qb[pi], kb[pi], vb[pi], abias, o);

    TA a{};
    a.o = o; a.xin = xin; a.xo = xout;
    a.wo = wo + (size_t)l * DM * DM;
    a.ln2s = ln2_s + l * DM; a.ln2b = ln2_b + l * DM;
    a.fw1 = ffn_w1 + (size_t)l * DM * DFF; a.fb1 = ffn_b1 + (size_t)l * DFF;
    a.fw2 = ffn_w2 + (size_t)l * DFF * DM; a.fb2 = ffn_b2 + (size_t)l * DM;
    if (l < NLAYER - 1) {
      a.wn0 = wq + (size_t)(l + 1) * DM * DM;
      a.wn1 = wk + (size_t)(l + 1) * DM * DM;
      a.wn2 = wv + (size_t)(l + 1) * DM * DM;
      a.lns = ln1_s + (l + 1) * DM; a.lnb = ln1_b + (l + 1) * DM;
      a.qo = qb[po]; a.ko = kb[po]; a.vo = vb[po];
      k_tail<0><<<192, 256, 0, stream>>>(a);
    } else {
      a.wn0 = pair_q_w; a.wn1 = pair_k_w;
      a.nb0 = pair_q_b; a.nb1 = pair_k_b;
      a.lns = lnf_s; a.lnb = lnf_b;
      a.qo = pq; a.ko = pk;
      k_tail<1><<<192, 256, 0, stream>>>(a);
    }
  }

  k_pair<<<dim3(24, 192), 256, PAIR_SMEM, stream>>>(pq, pk, W1p, RB, cls_w2, cls_b2, out);
}